// Round 10
// baseline (384.902 us; speedup 1.0000x reference)
//
#include <hip/hip_runtime.h>

// ---------------------------------------------------------------------------
// Mamba block. fp32 in/out. Internal: bf16 MFMA operands, fp32 accumulation
// and scan state.
// R21 (from R20 @ 349us): scan pass1/3 prefetch deepened, latency-matched.
// R20's depth-1 rotation left VALUBusy at 49% (pass3 45.9us): dt/u/z are
// HBM-latency (~900cyc) but had only ~275cyc cover. Now: scalars (dt/u/z)
// 4-deep (cover ~3 compute bodies ~825cyc), B/C vectors (L2-resident xdbl,
// ~200cyc) 2-deep ping-pong. Manual 4x unroll, named banks (static indices
// only). Identical numerics. All else = R20 (gemm8p GEMM1, 2-phase
// gemm_as<2,2> GEMM2, conv short8, wx partial+reduce, dt_mfma).
// ---------------------------------------------------------------------------
#define BATCH   2
#define SEQ     2048
#define DMODEL  1024
#define DINNER  2048
#define DSTATE  16
#define DTRANK  64
#define MROWS   (BATCH * SEQ)   // 4096
#define CLEN    64              // scan chunk length
#define CHUNKS  (SEQ / CLEN)    // 32

typedef float floatx4 __attribute__((ext_vector_type(4)));
typedef __bf16 bf16x8 __attribute__((ext_vector_type(8)));

__device__ __forceinline__ void async_cp16(void* lds, const void* g) {
    __builtin_amdgcn_global_load_lds((const __attribute__((address_space(1))) void*)g,
                                     (__attribute__((address_space(3))) void*)lds, 16, 0, 0);
}

// ---------------------------------------------------------------------------
// K0: fp32 -> bf16 weight conversion
// ---------------------------------------------------------------------------
__global__ __launch_bounds__(256) void w2bf(const float* __restrict__ w,
                                            __bf16* __restrict__ o, int n) {
    int i = (blockIdx.x * 256 + threadIdx.x) * 4;
    if (i < n) {
        floatx4 v = *(const floatx4*)&w[i];
        __bf16 r[4];
#pragma unroll
        for (int t = 0; t < 4; ++t) r[t] = (__bf16)v[t];
        *(unsigned long long*)&o[i] = *(unsigned long long*)r;
    }
}

// ---------------------------------------------------------------------------
// K1: LayerNorm.  One block per row of 1024.  fp32 in, bf16 out (GEMM A-op).
// ---------------------------------------------------------------------------
__global__ __launch_bounds__(256) void ln_kernel(const float* __restrict__ x,
                                                 const float* __restrict__ w,
                                                 const float* __restrict__ b,
                                                 __bf16* __restrict__ xn) {
    int row = blockIdx.x;
    const float* xr = x + (size_t)row * DMODEL;
    float v[4], s = 0.f, ss = 0.f;
#pragma unroll
    for (int i = 0; i < 4; ++i) {
        v[i] = xr[threadIdx.x + i * 256];
        s += v[i]; ss += v[i] * v[i];
    }
#pragma unroll
    for (int o = 32; o > 0; o >>= 1) { s += __shfl_xor(s, o); ss += __shfl_xor(ss, o); }
    __shared__ float ps[4], pss[4];
    int wv = threadIdx.x >> 6;
    if ((threadIdx.x & 63) == 0) { ps[wv] = s; pss[wv] = ss; }
    __syncthreads();
    s  = ps[0] + ps[1] + ps[2] + ps[3];
    ss = pss[0] + pss[1] + pss[2] + pss[3];
    float mu  = s * (1.f / DMODEL);
    float var = ss * (1.f / DMODEL) - mu * mu;
    float rs  = rsqrtf(var + 1e-5f);
#pragma unroll
    for (int i = 0; i < 4; ++i) {
        int c = threadIdx.x + i * 256;
        xn[(size_t)row * DMODEL + c] = (__bf16)((v[i] - mu) * rs * w[c] + b[c]);
    }
}

// ---------------------------------------------------------------------------
// K2a: 8-phase 256x256 GEMM (GEMM1).  C[M,N] = A[M,K] * B[N,K]^T, bf16 in.
// 512 thr = 8 waves (2M x 4N); wave owns 128x64 of C (acc[8][4]).
// LDS: 2 K-tile buffers x (A 256x64 + B 256x64) bf16 = 128 KiB.
// Stage slots per tile t: q0: B1(t+1)  q1: A0(t+2)  q2: A1(t+1)  q3: B0(t+2)
// Steady-state waits: q0: vmcnt(8), q1: vmcnt(6), q2: -, q3: vmcnt(8);
// tail tiles tighten per guards.  Source-side XOR swizzle (lane l loads
// 16B-group (l&7)^(l>>3) of row c*8+(l>>3); reads invert).
// EPI=1: split store -> out0 bf16 (n<split) / out1 bf16 (n>=split)
// ---------------------------------------------------------------------------
template <int EPI>
__global__ __launch_bounds__(512) void gemm8p(const __bf16* __restrict__ A,
                                              const __bf16* __restrict__ Bb,
                                              int M, int N, int K,
                                              __bf16* __restrict__ out0,
                                              __bf16* __restrict__ out1,
                                              int split) {
    __shared__ __align__(16) __bf16 sA[2][256 * 64];
    __shared__ __align__(16) __bf16 sB[2][256 * 64];
    const int NT = K >> 6;
    int tid = threadIdx.x, w = tid >> 6, lane = tid & 63;
    int wr = w >> 2, wc = w & 3;
    int lr = lane & 15, lq = lane >> 4;
    int srow = lane >> 3;
    int sg = ((lane & 7) ^ srow) * 8;

    // XCD-aware block swizzle (grid = 256, %8 == 0 -> bijective)
    int nbx = N >> 8;
    int cpx = gridDim.x >> 3;
    int wg = (blockIdx.x & 7) * cpx + (blockIdx.x >> 3);
    int by = wg / nbx, bx = wg % nbx;
    int m0 = by * 256, n0 = bx * 256;

    auto stageA = [&](int b, int t, int h) {
        int k0 = t * 64;
#pragma unroll
        for (int l = 0; l < 2; ++l) {
            int c = w * 2 + l;                                   // 0..15
            int base = (c >> 3) * 128 + h * 64 + (c & 7) * 8;    // chunk row base
            const __bf16* g = A + (size_t)(m0 + base + srow) * K + k0 + sg;
            async_cp16(&sA[b][base * 64], g);
        }
    };
    auto stageB = [&](int b, int t, int h) {
        int k0 = t * 64;
#pragma unroll
        for (int l = 0; l < 2; ++l) {
            int c = w * 2 + l;
            int base = (c >> 2) * 64 + h * 32 + (c & 3) * 8;
            const __bf16* g = Bb + (size_t)(n0 + base + srow) * K + k0 + sg;
            async_cp16(&sB[b][base * 64], g);
        }
    };

    floatx4 acc[8][4] = {};

    // Prologue issue order (chronological, matches steady-state ledger):
    // A0(0), B0(0), B1(0), A0(1), A1(0), B0(1)
    stageA(0, 0, 0); stageB(0, 0, 0); stageB(0, 0, 1);
    stageA(1, 1, 0); stageA(0, 0, 1); stageB(1, 1, 0);
    // due: A0(0),B0(0); allowed in flight: B1(0),A0(1),A1(0),B0(1) = 8 loads
    asm volatile("s_waitcnt vmcnt(8)" ::: "memory");
    __builtin_amdgcn_s_barrier();
    __builtin_amdgcn_sched_barrier(0);

    for (int t = 0; t < NT; ++t) {
        int b = t & 1;
        bf16x8 af[8], bfr[4];
#pragma unroll
        for (int q = 0; q < 4; ++q) {
            const int qi = q >> 1, qj = q & 1;
            if (qj == 0) {                                 // A-frags held across 2 phases
#pragma unroll
                for (int i = 0; i < 4; ++i)
#pragma unroll
                    for (int kh = 0; kh < 2; ++kh)
                        af[i * 2 + kh] = *(const bf16x8*)&sA[b][
                            (wr * 128 + qi * 64 + i * 16 + lr) * 64 +
                            (((kh * 4 + lq) ^ (lr & 7)) * 8)];
            }
#pragma unroll
            for (int j = 0; j < 2; ++j)
#pragma unroll
                for (int kh = 0; kh < 2; ++kh)
                    bfr[j * 2 + kh] = *(const bf16x8*)&sB[b][
                        (wc * 64 + (qj * 2 + j) * 16 + lr) * 64 +
                        (((kh * 4 + lq) ^ (lr & 7)) * 8)];

            // stage slot (region freed by prior phases' barriers)
            if      (q == 0) { if (t + 1 < NT) stageB(b ^ 1, t + 1, 1); }
            else if (q == 1) { if (t + 2 < NT) stageA(b,     t + 2, 0); }
            else if (q == 2) { if (t + 1 < NT) stageA(b ^ 1, t + 1, 1); }
            else             { if (t + 2 < NT) stageB(b,     t + 2, 0); }

            __builtin_amdgcn_sched_barrier(0);
            __builtin_amdgcn_s_barrier();
            __builtin_amdgcn_sched_barrier(0);

            __builtin_amdgcn_s_setprio(1);
#pragma unroll
            for (int i = 0; i < 4; ++i)
#pragma unroll
                for (int j = 0; j < 2; ++j)
#pragma unroll
                    for (int kh = 0; kh < 2; ++kh)
                        acc[qi * 4 + i][qj * 2 + j] = __builtin_amdgcn_mfma_f32_16x16x32_bf16(
                            af[i * 2 + kh], bfr[j * 2 + kh], acc[qi * 4 + i][qj * 2 + j], 0, 0, 0);
            __builtin_amdgcn_s_setprio(0);
            __builtin_amdgcn_sched_barrier(0);

            // counted waits (deadline ledger; never 0 in steady state)
            if (q == 0) {
                if (t + 1 < NT) asm volatile("s_waitcnt vmcnt(8)" ::: "memory");
                else            asm volatile("s_waitcnt vmcnt(2)" ::: "memory");
            } else if (q == 1) {
                if      (t + 2 < NT) asm volatile("s_waitcnt vmcnt(6)" ::: "memory");
                else if (t + 1 < NT) asm volatile("s_waitcnt vmcnt(4)" ::: "memory");
                else                 asm volatile("s_waitcnt vmcnt(0)" ::: "memory");
            } else if (q == 3) {
                if      (t + 2 < NT) asm volatile("s_waitcnt vmcnt(8)" ::: "memory");
                else if (t + 1 < NT) asm volatile("s_waitcnt vmcnt(4)" ::: "memory");
            }
            __builtin_amdgcn_s_barrier();
            __builtin_amdgcn_sched_barrier(0);
        }
    }

    // Epilogue: split bf16 store (n < split -> out0, else out1)
#pragma unroll
    for (int i = 0; i < 8; ++i)
#pragma unroll
        for (int j = 0; j < 4; ++j) {
            int gn = n0 + wc * 64 + j * 16 + lr;
#pragma unroll
            for (int r = 0; r < 4; ++r) {
                int gm = m0 + wr * 128 + i * 16 + lq * 4 + r;
                float v = acc[i][j][r];
                if (gn < split) out0[(size_t)gm * split + gn] = (__bf16)v;
                else            out1[(size_t)gm * (N - split) + (gn - split)] = (__bf16)v;
            }
        }
}

// ---------------------------------------------------------------------------
// K2b: GEMM2, T3 minimum-2-phase: double-buffered LDS, next K-tile staged
// BEFORE compute, ONE vmcnt(0)+barrier per K-step.  NW=2: 128x64 tile,
// 512 blocks = 2/CU.  LDS 2x24KB = 48KB.
// EPI=2: residual -> outf fp32 = acc + add[idx]
// ---------------------------------------------------------------------------
template <int EPI, int NW>
__global__ __launch_bounds__(256) void gemm_as(const __bf16* __restrict__ A,
                                               const __bf16* __restrict__ Bb,
                                               int M, int N, int K,
                                               __bf16* __restrict__ out0,
                                               __bf16* __restrict__ out1,
                                               float* __restrict__ outf,
                                               const float* __restrict__ add,
                                               int split) {
    constexpr int BNT = NW * 32;
    constexpr int ACH = 16;                      // A chunks per K-step (128r x 128B)
    constexpr int NCH = ACH + BNT / 8;           // + B chunks
    __shared__ __align__(16) __bf16 sA[2][128 * 64];
    __shared__ __align__(16) __bf16 sB[2][BNT * 64];
    int tid  = threadIdx.x;
    int wave = tid >> 6, lane = tid & 63;
    int m0 = blockIdx.y * 128, n0 = blockIdx.x * BNT;
    int wm = (wave & 1) * 64, wn = (wave >> 1) * (NW * 16);
    int lr = lane & 15;
    int lq = lane >> 4;
    int srow = lane >> 3;                        // row within a chunk (0..7)
    int sg   = ((lane & 7) ^ srow) * 8;          // swizzled source elem group

    auto stage = [&](int b, int k0) {
        for (int c = wave; c < NCH; c += 4) {
            if (c < ACH) {
                const __bf16* g = A + (size_t)(m0 + c * 8 + srow) * K + k0 + sg;
                async_cp16(&sA[b][c * 512], g);
            } else {
                int cb = c - ACH;
                const __bf16* g = Bb + (size_t)(n0 + cb * 8 + srow) * K + k0 + sg;
                async_cp16(&sB[b][cb * 512], g);
            }
        }
    };

    floatx4 acc[4][NW] = {};

    stage(0, 0);
    __builtin_amdgcn_sched_barrier(0);
    asm volatile("s_waitcnt vmcnt(0)" ::: "memory");
    __builtin_amdgcn_s_barrier();
    __builtin_amdgcn_sched_barrier(0);

    int cur = 0;
    for (int k0 = 0; k0 < K; k0 += 64) {
        if (k0 + 64 < K) stage(cur ^ 1, k0 + 64);   // prefetch overlaps compute

#pragma unroll
        for (int s = 0; s < 2; ++s) {
            bf16x8 af[4], bfr[NW];
#pragma unroll
            for (int i = 0; i < 4; ++i) {
                int row = wm + i * 16 + lr;
                af[i] = *(const bf16x8*)&sA[cur][row * 64 + (((s * 4 + lq) ^ (lr & 7)) * 8)];
            }
#pragma unroll
            for (int j = 0; j < NW; ++j) {
                int row = wn + j * 16 + lr;
                bfr[j] = *(const bf16x8*)&sB[cur][row * 64 + (((s * 4 + lq) ^ (lr & 7)) * 8)];
            }
#pragma unroll
            for (int i = 0; i < 4; ++i)
#pragma unroll
                for (int j = 0; j < NW; ++j)
                    acc[i][j] = __builtin_amdgcn_mfma_f32_16x16x32_bf16(af[i], bfr[j], acc[i][j], 0, 0, 0);
        }

        __builtin_amdgcn_sched_barrier(0);
        asm volatile("s_waitcnt vmcnt(0)" ::: "memory");
        __builtin_amdgcn_s_barrier();
        __builtin_amdgcn_sched_barrier(0);
        cur ^= 1;
    }

#pragma unroll
    for (int i = 0; i < 4; ++i)
#pragma unroll
        for (int j = 0; j < NW; ++j) {
            int gn = n0 + wn + j * 16 + lr;
#pragma unroll
            for (int r = 0; r < 4; ++r) {
                int gm = m0 + wm + i * 16 + lq * 4 + r;
                float v = acc[i][j][r];
                if (EPI == 1) {
                    if (gn < split) out0[(size_t)gm * split + gn] = (__bf16)v;
                    else            out1[(size_t)gm * split + (gn - split)] = (__bf16)v;
                } else {
                    size_t idx = (size_t)gm * N + gn;
                    outf[idx] = v + add[idx];
                }
            }
        }
}

// ---------------------------------------------------------------------------
// K3: depthwise causal conv (width 4) + bias + SiLU.  short8-vectorized:
// thread = 8 consecutive channels of one (b,l) row; 4 bf16x8 row loads.
// ---------------------------------------------------------------------------
__global__ __launch_bounds__(256) void conv_kernel(const __bf16* __restrict__ xin,
                                                   const float* __restrict__ cw,
                                                   const float* __restrict__ cb,
                                                   __bf16* __restrict__ u) {
    int t8 = blockIdx.x * 256 + threadIdx.x;         // over MROWS*DINNER/8
    int dg = t8 & (DINNER / 8 - 1);
    int bl = t8 >> 8;                                // b*SEQ + l
    int l  = bl & (SEQ - 1);
    int d0 = dg * 8;
    float acc[8];
#pragma unroll
    for (int k = 0; k < 8; ++k) acc[k] = cb[d0 + k];
    float wgt[8][4];
#pragma unroll
    for (int k = 0; k < 8; ++k) {
        floatx4 wv = *(const floatx4*)&cw[(d0 + k) * 4];
#pragma unroll
        for (int j = 0; j < 4; ++j) wgt[k][j] = wv[j];
    }
#pragma unroll
    for (int j = 0; j < 4; ++j) {
        int ll = l - 3 + j;
        if (ll >= 0) {
            bf16x8 v = *(const bf16x8*)&xin[(size_t)(bl - 3 + j) * DINNER + d0];
#pragma unroll
            for (int k = 0; k < 8; ++k) acc[k] += (float)v[k] * wgt[k][j];
        }
    }
    __bf16 r[8];
#pragma unroll
    for (int k = 0; k < 8; ++k) {
        float sg = 1.f / (1.f + __expf(-acc[k]));
        r[k] = (__bf16)(acc[k] * sg);
    }
    *(bf16x8*)&u[(size_t)bl * DINNER + d0] = *(bf16x8*)r;
}

// ---------------------------------------------------------------------------
// K4 (MFMA, split-K): P[ks][4096,96] = u[4096,2048](K-slice ks) @ Wx^T.
// Partial STORES (no atomics).  WX_KS=8 -> partials 12 MiB.  wx_reduce sums.
// ---------------------------------------------------------------------------
#define BM 128
#define BN 128
#define BK 32
#define LDK 48
#define WX_KS 8
#define WX_KSLICE (DINNER / WX_KS)   // 256

__global__ __launch_bounds__(256) void wx_mfma(const __bf16* __restrict__ A,
                                               const float* __restrict__ B,
                                               float* __restrict__ P) {
    __shared__ __align__(16) __bf16 sA[BM][LDK];
    __shared__ __align__(16) __bf16 sB[96][LDK];
    int tid  = threadIdx.x;
    int wave = tid >> 6, lane = tid & 63;
    int m0 = blockIdx.x * BM;
    int k0base = blockIdx.y * WX_KSLICE;
    int wm = (wave & 1) * 64, wn = (wave >> 1) * 48;
    int lr = lane & 15;
    int lq = lane >> 4;

    floatx4 acc[4][3] = {};

    for (int k0 = k0base; k0 < k0base + WX_KSLICE; k0 += BK) {
#pragma unroll
        for (int c = tid; c < 512; c += 256) {
            int row = c >> 2, col = (c & 3) * 8;
            *(bf16x8*)&sA[row][col] = *(const bf16x8*)&A[(size_t)(m0 + row) * DINNER + k0 + col];
        }
        for (int c = tid; c < 384; c += 256) {
            int row = c >> 2, col = (c & 3) * 8;
            const float* src = B + (size_t)row * DINNER + k0 + col;
            floatx4 lo = *(const floatx4*)src;
            floatx4 hi = *(const floatx4*)(src + 4);
            bf16x8 v;
#pragma unroll
            for (int t = 0; t < 4; ++t) { v[t] = (__bf16)lo[t]; v[4 + t] = (__bf16)hi[t]; }
            *(bf16x8*)&sB[row][col] = v;
        }
        __syncthreads();

        bf16x8 af[4], bfr[3];
#pragma unroll
        for (int i = 0; i < 4; ++i) af[i]  = *(const bf16x8*)&sA[wm + i * 16 + lr][lq * 8];
#pragma unroll
        for (int j = 0; j < 3; ++j) bfr[j] = *(const bf16x8*)&sB[wn + j * 16 + lr][lq * 8];
#pragma unroll
        for (int i = 0; i < 4; ++i)
#pragma unroll
            for (int j = 0; j < 3; ++j)
                acc[i][j] = __builtin_amdgcn_mfma_f32_16x16x32_bf16(af[i], bfr[j], acc[i][j], 0, 0, 0);
        __syncthreads();
    }

    float* Pk = P + (size_t)blockIdx.y * (MROWS * 96);
#pragma unroll
    for (int i = 0; i < 4; ++i)
#pragma unroll
        for (int j = 0; j < 3; ++j) {
            int gn = wn + j * 16 + lr;
#pragma unroll
            for (int r = 0; r < 4; ++r) {
                int gm = m0 + wm + i * 16 + lq * 4 + r;
                Pk[(size_t)gm * 96 + gn] = acc[i][j][r];
            }
        }
}

__global__ __launch_bounds__(256) void wx_reduce(const float* __restrict__ P,
                                                 float* __restrict__ xdbl) {
    int i = (blockIdx.x * 256 + threadIdx.x) * 4;    // over MROWS*96
    floatx4 s = *(const floatx4*)&P[i];
#pragma unroll
    for (int k = 1; k < WX_KS; ++k) {
        floatx4 v = *(const floatx4*)&P[(size_t)k * (MROWS * 96) + i];
        s += v;
    }
    *(floatx4*)&xdbl[i] = s;
}

// ---------------------------------------------------------------------------
// K5 (MFMA): dt[4096,2048] = softplus(xdbl[:,0:64] @ Wdt[2048,64]^T + b_dt)
// ---------------------------------------------------------------------------
__global__ __launch_bounds__(256) void dt_mfma(const float* __restrict__ Af,
                                               const float* __restrict__ B,
                                               const float* __restrict__ bdt,
                                               __bf16* __restrict__ dt) {
    __shared__ __align__(16) __bf16 sA[BM][LDK];
    __shared__ __align__(16) __bf16 sB[BN][LDK];
    int tid  = threadIdx.x;
    int wave = tid >> 6, lane = tid & 63;
    int m0 = blockIdx.y * BM, n0 = blockIdx.x * BN;
    int wm = (wave & 1) * 64, wn = (wave >> 1) * 64;
    int lr = lane & 15;
    int lq = lane >> 4;

    floatx4 acc[4][4] = {};

    for (int k0 = 0; k0 < DTRANK; k0 += BK) {
#pragma unroll
        for (int c = tid; c < 512; c += 256) {
            int row = c >> 2, col = (c & 3) * 8;
            const float* src = Af + (size_t)(m0 + row) * 96 + k0 + col;
            floatx4 lo = *(const floatx4*)src;
            floatx4 hi = *(const floatx4*)(src + 4);
            bf16x8 v;
#pragma unroll
            for (int t = 0; t < 4; ++t) { v[t] = (__bf16)lo[t]; v[4 + t] = (__bf16)hi[t]; }
            *(bf16x8*)&sA[row][col] = v;
        }
#pragma unroll
        for (int c = tid; c < 512; c += 256) {
            int row = c >> 2, col = (c & 3) * 8;
            const float* src = B + (size_t)(n0 + row) * DTRANK + k0 + col;
            floatx4 lo = *(const floatx4*)src;
            floatx4 hi = *(const floatx4*)(src + 4);
            bf16x8 v;
#pragma unroll
            for (int t = 0; t < 4; ++t) { v[t] = (__bf16)lo[t]; v[4 + t] = (__bf16)hi[t]; }
            *(bf16x8*)&sB[row][col] = v;
        }
        __syncthreads();

        bf16x8 af[4], bfr[4];
#pragma unroll
        for (int i = 0; i < 4; ++i) af[i]  = *(const bf16x8*)&sA[wm + i * 16 + lr][lq * 8];
#pragma unroll
        for (int j = 0; j < 4; ++j) bfr[j] = *(const bf16x8*)&sB[wn + j * 16 + lr][lq * 8];
#pragma unroll
        for (int i = 0; i < 4; ++i)
#pragma unroll
            for (int j = 0; j < 4; ++j)
                acc[i][j] = __builtin_amdgcn_mfma_f32_16x16x32_bf16(af[i], bfr[j], acc[i][j], 0, 0, 0);
        __syncthreads();
    }

#pragma unroll
    for (int i = 0; i < 4; ++i)
#pragma unroll
        for (int j = 0; j < 4; ++j) {
            int gn = n0 + wn + j * 16 + lr;
            float bv = bdt[gn];
#pragma unroll
            for (int r = 0; r < 4; ++r) {
                int gm = m0 + wm + i * 16 + lq * 4 + r;
                float a = acc[i][j][r] + bv;
                float sp = (a > 20.f) ? a : log1pf(__expf(a));
                dt[(size_t)gm * DINNER + gn] = (__bf16)sp;
            }
        }
}

// ---------------------------------------------------------------------------
// K6 (3-pass chunked scan), LDS-free.  Wave = 64 consecutive channels,
// 16 states/lane.  R21: latency-matched prefetch -- scalars (dt/u/z, HBM
// ~900cyc) 4-deep; B/C vectors (xdbl L2-resident ~200cyc) 2-deep ping-pong.
// Manual 4x unroll with named banks (all register indices static).
// ---------------------------------------------------------------------------
__device__ __forceinline__ void scan_step1(float dtv, float uv,
                                           const floatx4& B0, const floatx4& B1,
                                           const floatx4& B2, const floatx4& B3,
                                           const float* A, float* h, float& S) {
    S += dtv;
    float du = dtv * uv;
#pragma unroll
    for (int s = 0; s < 4; ++s) {
        h[s]      = __expf(dtv * A[s])      * h[s]      + du * B0[s];
        h[4 + s]  = __expf(dtv * A[4 + s])  * h[4 + s]  + du * B1[s];
        h[8 + s]  = __expf(dtv * A[8 + s])  * h[8 + s]  + du * B2[s];
        h[12 + s] = __expf(dtv * A[12 + s]) * h[12 + s] + du * B3[s];
    }
}

#define LDB1(bank, tt)                                     \
    bank##0 = *(const floatx4*)(bcp + (tt) * 96);          \
    bank##1 = *(const floatx4*)(bcp + (tt) * 96 + 4);      \
    bank##2 = *(const floatx4*)(bcp + (tt) * 96 + 8);      \
    bank##3 = *(const floatx4*)(bcp + (tt) * 96 + 12);

__global__ __launch_bounds__(64) void scan_pass1(const __bf16* __restrict__ dt,
                                                 const __bf16* __restrict__ u,
                                                 const float* __restrict__ xdbl,
                                                 const float* __restrict__ Alog,
                                                 float* __restrict__ Sdt,
                                                 __bf16* __restrict__ Hfix) {
    int c = blockIdx.x, dblk = blockIdx.y, b = blockIdx.z;
    int lane = threadIdx.x;
    int d = dblk * 64 + lane;
    int row0 = b * SEQ + c * CLEN;

    const __bf16* dtp = dt + (size_t)row0 * DINNER + d;
    const __bf16* up  = u  + (size_t)row0 * DINNER + d;
    const float*  bcp = xdbl + (size_t)row0 * 96 + 64;

    float A[DSTATE], h[DSTATE];
#pragma unroll
    for (int s = 0; s < DSTATE; ++s) { A[s] = -__expf(Alog[d * DSTATE + s]); h[s] = 0.f; }

    float S = 0.f;
    // scalar pipeline: 4 deep; B pipeline: 2 banks ping-pong
    float dv0 = (float)dtp[0],           uv0 = (float)up[0];
    float dv1 = (float)dtp[DINNER],      uv1 = (float)up[DINNER];
    float dv2 = (float)dtp[2 * DINNER],  uv2 = (float)up[2 * DINNER];
    float dv3 = (float)dtp[3 * DINNER],  uv3 = (float)up[3 * DINNER];
    floatx4 bA0, bA1, bA2, bA3, bB0, bB1, bB2, bB3;
    LDB1(bA, 0)
    LDB1(bB, 1)
    for (int t = 0; t < CLEN; t += 4) {
        scan_step1(dv0, uv0, bA0, bA1, bA2, bA3, A, h, S);
        if (t + 2 < CLEN) { LDB1(bA, t + 2) }
        if (t + 4 < CLEN) { dv0 = (float)dtp[(size_t)(t + 4) * DINNER]; uv0 = (float)up[(size_t)(t + 4) * DINNER]; }
        scan_step1(dv1, uv1, bB0, bB1, bB2, bB3, A, h, S);
        if (t + 3 < CLEN) { LDB1(bB, t + 3) }
        if (t + 5 < CLEN) { dv1 = (float)dtp[(size_t)(t + 5) * DINNER]; uv1 = (float)up[(size_t)(t + 5) * DINNER]; }
        scan_step1(dv2, uv2, bA0, bA1, bA2, bA3, A, h, S);
        if (t + 4 < CLEN) { LDB1(bA, t + 4) }
        if (t + 6 < CLEN) { dv2 = (float)dtp[(size_t)(t + 6) * DINNER]; uv2 = (float)up[(size_t)(t + 6) * DINNER]; }
        scan_step1(dv3, uv3, bB0, bB1, bB2, bB3, A, h, S);
        if (t + 5 < CLEN) { LDB1(bB, t + 5) }
        if (t + 7 < CLEN) { dv3 = (float)dtp[(size_t)(t + 7) * DINNER]; uv3 = (float)up[(size_t)(t + 7) * DINNER]; }
    }
    size_t ch = ((size_t)(b * DINNER + d) * CHUNKS + c);
    Sdt[ch] = S;
#pragma unroll
    for (int s = 0; s < DSTATE; ++s) Hfix[ch * DSTATE + s] = (__bf16)h[s];
}

__global__ __launch_bounds__(256) void scan_pass2(const float* __restrict__ Alog,
                                                  const float* __restrict__ Sdt,
                                                  __bf16* __restrict__ Hfix) {
    int g = blockIdx.x * 256 + threadIdx.x;       // over BATCH*DINNER*DSTATE
    int s = g & (DSTATE - 1);
    int bd = g >> 4;
    int d = bd & (DINNER - 1);
    float A = -__expf(Alog[d * DSTATE + s]);
    size_t hbase = (size_t)bd * CHUNKS * DSTATE + s;
    size_t sbase = (size_t)bd * CHUNKS;
    float h = 0.f;
#pragma unroll 4
    for (int c = 0; c < CHUNKS; ++c) {
        float Hl = (float)Hfix[hbase + c * DSTATE];
        float P  = __expf(A * Sdt[sbase + c]);
        Hfix[hbase + c * DSTATE] = (__bf16)h;
        h = P * h + Hl;
    }
}

__device__ __forceinline__ void scan_step3(float dtv, float uv, float zv,
                                           const floatx4& B0, const floatx4& B1,
                                           const floatx4& B2, const floatx4& B3,
                                           const floatx4& C0, const floatx4& C1,
                                           const floatx4& C2, const floatx4& C3,
                                           const float* A, float* h, float Dv,
                                           __bf16* zyp, int t) {
    float du = dtv * uv;
    float yv = 0.f;
#pragma unroll
    for (int s = 0; s < 4; ++s) {
        h[s]      = __expf(dtv * A[s])      * h[s]      + du * B0[s];
        h[4 + s]  = __expf(dtv * A[4 + s])  * h[4 + s]  + du * B1[s];
        h[8 + s]  = __expf(dtv * A[8 + s])  * h[8 + s]  + du * B2[s];
        h[12 + s] = __expf(dtv * A[12 + s]) * h[12 + s] + du * B3[s];
        yv += h[s] * C0[s] + h[4 + s] * C1[s] + h[8 + s] * C2[s] + h[12 + s] * C3[s];
    }
    float sg = zv / (1.f + __expf(-zv));
    zyp[(size_t)t * DINNER] = (__bf16)((yv + uv * Dv) * sg);
}

#define LDBC3(bank, tt)                                    \
    bank##B0 = *(const floatx4*)(bcp + (tt) * 96);         \
    bank##B1 = *(const floatx4*)(bcp + (tt) * 96 + 4);     \
    bank##B2 = *(const floatx4*)(bcp + (tt) * 96 + 8);     \
    bank##B3 = *(const floatx4*)(bcp + (tt) * 96 + 12);    \
    bank##C0 = *(const floatx4*)(bcp + (tt) * 96 + 16);    \
    bank##C1 = *(const floatx4*)(bcp + (tt) * 96 + 20);    \
    bank##C2 = *(const floatx4*)(bcp + (tt) * 96 + 24);    \
    bank##C3 = *(const floatx4*)(bcp + (tt) * 96 + 28);

__global__ __launch_bounds__(64) void scan_pass3(const __bf16* __restrict__ dt,
                                                 const __bf16* __restrict__ u,
                                                 const float* __restrict__ xdbl,
                                                 const float* __restrict__ Alog,
                                                 const float* __restrict__ Dp,
                                                 const __bf16* __restrict__ Hfix,
                                                 __bf16* zy) {
    int c = blockIdx.x, dblk = blockIdx.y, b = blockIdx.z;
    int lane = threadIdx.x;
    int d = dblk * 64 + lane;
    int row0 = b * SEQ + c * CLEN;

    const __bf16* dtp = dt + (size_t)row0 * DINNER + d;
    const __bf16* up  = u  + (size_t)row0 * DINNER + d;
    __bf16*       zyp = zy + (size_t)row0 * DINNER + d;
    const float*  bcp = xdbl + (size_t)row0 * 96 + 64;

    float A[DSTATE], h[DSTATE];
    size_t ch = ((size_t)(b * DINNER + d) * CHUNKS + c);
#pragma unroll
    for (int s = 0; s < DSTATE; ++s) {
        A[s] = -__expf(Alog[d * DSTATE + s]);
        h[s] = (float)Hfix[ch * DSTATE + s];
    }
    float Dv = Dp[d];

    // scalar pipeline: 4 deep; B/C pipeline: 2 banks ping-pong
    float dv0 = (float)dtp[0],          uv0 = (float)up[0],          zv0 = (float)zyp[0];
    float dv1 = (float)dtp[DINNER],     uv1 = (float)up[DINNER],     zv1 = (float)zyp[DINNER];
    float dv2 = (float)dtp[2 * DINNER], uv2 = (float)up[2 * DINNER], zv2 = (float)zyp[2 * DINNER];
    float dv3 = (float)dtp[3 * DINNER], uv3 = (float)up[3 * DINNER], zv3 = (float)zyp[3 * DINNER];
    floatx4 aB0, aB1, aB2, aB3, aC0, aC1, aC2, aC3;
    floatx4 eB0, eB1, eB2, eB3, eC0, eC1, eC2, eC3;
    LDBC3(a, 0)
    LDBC3(e, 1)
    for (int t = 0; t < CLEN; t += 4) {
        scan_step3(dv0, uv0, zv0, aB0, aB1, aB2, aB3, aC0, aC1, aC2, aC3, A, h, Dv, zyp, t);
        if (t + 2 < CLEN) { LDBC3(a, t + 2) }
        if (t + 4 < CLEN) {
            dv0 = (float)dtp[(size_t)(t + 4) * DINNER];
            uv0 = (float)up [(size_t)(t + 4) * DINNER];
            zv0 = (float)zyp[(size_t)(t + 4) * DINNER];
        }
        scan_step3(dv1, uv1, zv1, eB0, eB1, eB2, eB3, eC0, eC1, eC2, eC3, A, h, Dv, zyp, t + 1);
        if (t + 3 < CLEN) { LDBC3(e, t + 3) }
        if (t + 5 < CLEN) {
            dv1 = (float)dtp[(size_t)(t + 5) * DINNER];
            uv1 = (float)up [(size_t)(t + 5) * DINNER];
            zv1 = (float)zyp[(size_t)(t + 5) * DINNER];
        }
        scan_step3(dv2, uv2, zv2, aB0, aB1, aB2, aB3, aC0, aC1, aC2, aC3, A, h, Dv, zyp, t + 2);
        if (t + 4 < CLEN) { LDBC3(a, t + 4) }
        if (t + 6 < CLEN) {
            dv2 = (float)dtp[(size_t)(t + 6) * DINNER];
            uv2 = (float)up [(size_t)(t + 6) * DINNER];
            zv2 = (float)zyp[(size_t)(t + 6) * DINNER];
        }
        scan_step3(dv3, uv3, zv3, eB0, eB1, eB2, eB3, eC0, eC1, eC2, eC3, A, h, Dv, zyp, t + 3);
        if (t + 5 < CLEN) { LDBC3(e, t + 5) }
        if (t + 7 < CLEN) {
            dv3 = (float)dtp[(size_t)(t + 7) * DINNER];
            uv3 = (float)up [(size_t)(t + 7) * DINNER];
            zv3 = (float)zyp[(size_t)(t + 7) * DINNER];
        }
    }
}

// ---------------------------------------------------------------------------
extern "C" void kernel_launch(void* const* d_in, const int* in_sizes, int n_in,
                              void* d_out, int out_size, void* d_ws, size_t ws_size,
                              hipStream_t stream) {
    const float* x      = (const float*)d_in[0];
    const float* ln_w   = (const float*)d_in[1];
    const float* ln_b   = (const float*)d_in[2];
    const float* W_in   = (const float*)d_in[3];
    const float* conv_w = (const float*)d_in[4];
    const float* conv_b = (const float*)d_in[5];
    const float* W_x    = (const float*)d_in[6];
    const float* W_dt   = (const float*)d_in[7];
    const float* b_dt   = (const float*)d_in[8];
    const float* A_log  = (const float*)d_in[9];
    const float* Dp     = (const float*)d_in[10];
    const float* W_out  = (const float*)d_in[11];
    float* out = (float*)d_out;

    // Workspace, 56 MiB peak:
    //   [ 0,  8M)  xn bf16 (dead after GEMM1) -> { xdbl fp32 [0,1.5M),
    //              Sdt fp32 [1.5M,2M), Hfix bf16 [2M,6M) }
    //   [ 8M,24M)  x_in bf16 (dead after conv) -> wxP fp32 12M (wx..reduce)
    //              -> dt bf16 (dt_mfma..pass3)
    //   [24M,40M)  z bf16; scan pass3 overwrites with y in place
    //   [40M,56M)  Winb bf16 8M (dead after GEMM1) -> u bf16 16M (conv..pass3)
    //              -> Woutb bf16 4M (after pass3)
    char* ws = (char*)d_ws;
    __bf16* xn_bf  = (__bf16*)(ws);
    float*  xdbl   = (float*) (ws);
    float*  Sdt    = (float*) (ws + 1536ull * 1024);
    __bf16* Hfix   = (__bf16*)(ws + (2ull  << 20));
    __bf16* xin_bf = (__bf16*)(ws + (8ull  << 20));
    float*  wxP    = (float*) (ws + (8ull  << 20));
    __bf16* dt_bf  = (__bf16*)(ws + (8ull  << 20));
    __bf16* zy_bf  = (__bf16*)(ws + (24ull << 20));
    __bf16* Winb   = (__bf16*)(ws + (40ull << 20));
    __bf16* u_bf   = (__bf16*)(ws + (40ull << 20));
    __bf16* Woutb  = (__bf16*)(ws + (40ull << 20));

    ln_kernel<<<MROWS, 256, 0, stream>>>(x, ln_w, ln_b, xn_bf);

    w2bf<<<(2 * DINNER * DMODEL) / 1024, 256, 0, stream>>>(W_in, Winb, 2 * DINNER * DMODEL);

    // GEMM1: 8-phase 256x256 template, grid = 16x16 = 256 blocks (1/CU)
    gemm8p<1><<<(MROWS / 256) * (2 * DINNER / 256), 512, 0, stream>>>(
        xn_bf, Winb, MROWS, 2 * DINNER, DMODEL, xin_bf, zy_bf, DINNER);

    conv_kernel<<<MROWS * DINNER / (8 * 256), 256, 0, stream>>>(xin_bf, conv_w, conv_b, u_bf);

    // wx: split-K partial stores (no atomics, no memset), then reduce
    wx_mfma<<<dim3(MROWS / BM, WX_KS), 256, 0, stream>>>(u_bf, W_x, wxP);
    wx_reduce<<<(MROWS * 96) / 1024, 256, 0, stream>>>(wxP, xdbl);

    dt_mfma<<<dim3(DINNER / BN, MROWS / BM), 256, 0, stream>>>(xdbl, W_dt, b_dt, dt_bf);

    dim3 sgrid(CHUNKS, DINNER / 64, BATCH);
    scan_pass1<<<sgrid, 64, 0, stream>>>(dt_bf, u_bf, xdbl, A_log, Sdt, Hfix);
    scan_pass2<<<BATCH * DINNER * DSTATE / 256, 256, 0, stream>>>(A_log, Sdt, Hfix);
    scan_pass3<<<sgrid, 64, 0, stream>>>(dt_bf, u_bf, xdbl, A_log, Dp, Hfix, zy_bf);

    w2bf<<<(DMODEL * DINNER) / 1024, 256, 0, stream>>>(W_out, Woutb, DMODEL * DINNER);

    // GEMM2: gemm_as NW=2 double-buffered prefetch (512 blocks = 2/CU)
    gemm_as<2, 2><<<dim3(DMODEL / 64, MROWS / 128), 256, 0, stream>>>(
        zy_bf, Woutb, MROWS, DMODEL, DINNER, nullptr, nullptr, out, x, 0);
}

// Round 11
// 337.012 us; speedup vs baseline: 1.1421x; 1.1421x over previous
//
#include <hip/hip_runtime.h>

// ---------------------------------------------------------------------------
// Mamba block. fp32 in/out. Internal: bf16 MFMA operands, fp32 accumulation
// and scan state.
// R22 (from best R20 @ 349us; R21's deep-bank pipeline REVERTED -- guards
// inside the loop fragmented basic blocks, compiler dropped the banks,
// pass3 46->67us). Scan change: CLEN 64->32 (CHUNKS=64) -> 2x scan waves
// (2048->4096 = 16/CU) for latency hiding; per-t code is the R20-proven
// depth-1 rotation, bit-identical numerics. Hfix (8.4MB @ CHUNKS=64) moved
// into d_out (dead until GEMM2 fully overwrites it). All else = R20.
// ---------------------------------------------------------------------------
#define BATCH   2
#define SEQ     2048
#define DMODEL  1024
#define DINNER  2048
#define DSTATE  16
#define DTRANK  64
#define MROWS   (BATCH * SEQ)   // 4096
#define CLEN    32              // scan chunk length (R22: was 64)
#define CHUNKS  (SEQ / CLEN)    // 64

typedef float floatx4 __attribute__((ext_vector_type(4)));
typedef __bf16 bf16x8 __attribute__((ext_vector_type(8)));

__device__ __forceinline__ void async_cp16(void* lds, const void* g) {
    __builtin_amdgcn_global_load_lds((const __attribute__((address_space(1))) void*)g,
                                     (__attribute__((address_space(3))) void*)lds, 16, 0, 0);
}

// ---------------------------------------------------------------------------
// K0: fp32 -> bf16 weight conversion
// ---------------------------------------------------------------------------
__global__ __launch_bounds__(256) void w2bf(const float* __restrict__ w,
                                            __bf16* __restrict__ o, int n) {
    int i = (blockIdx.x * 256 + threadIdx.x) * 4;
    if (i < n) {
        floatx4 v = *(const floatx4*)&w[i];
        __bf16 r[4];
#pragma unroll
        for (int t = 0; t < 4; ++t) r[t] = (__bf16)v[t];
        *(unsigned long long*)&o[i] = *(unsigned long long*)r;
    }
}

// ---------------------------------------------------------------------------
// K1: LayerNorm.  One block per row of 1024.  fp32 in, bf16 out (GEMM A-op).
// ---------------------------------------------------------------------------
__global__ __launch_bounds__(256) void ln_kernel(const float* __restrict__ x,
                                                 const float* __restrict__ w,
                                                 const float* __restrict__ b,
                                                 __bf16* __restrict__ xn) {
    int row = blockIdx.x;
    const float* xr = x + (size_t)row * DMODEL;
    float v[4], s = 0.f, ss = 0.f;
#pragma unroll
    for (int i = 0; i < 4; ++i) {
        v[i] = xr[threadIdx.x + i * 256];
        s += v[i]; ss += v[i] * v[i];
    }
#pragma unroll
    for (int o = 32; o > 0; o >>= 1) { s += __shfl_xor(s, o); ss += __shfl_xor(ss, o); }
    __shared__ float ps[4], pss[4];
    int wv = threadIdx.x >> 6;
    if ((threadIdx.x & 63) == 0) { ps[wv] = s; pss[wv] = ss; }
    __syncthreads();
    s  = ps[0] + ps[1] + ps[2] + ps[3];
    ss = pss[0] + pss[1] + pss[2] + pss[3];
    float mu  = s * (1.f / DMODEL);
    float var = ss * (1.f / DMODEL) - mu * mu;
    float rs  = rsqrtf(var + 1e-5f);
#pragma unroll
    for (int i = 0; i < 4; ++i) {
        int c = threadIdx.x + i * 256;
        xn[(size_t)row * DMODEL + c] = (__bf16)((v[i] - mu) * rs * w[c] + b[c]);
    }
}

// ---------------------------------------------------------------------------
// K2a: 8-phase 256x256 GEMM (GEMM1).  C[M,N] = A[M,K] * B[N,K]^T, bf16 in.
// 512 thr = 8 waves (2M x 4N); wave owns 128x64 of C (acc[8][4]).
// LDS: 2 K-tile buffers x (A 256x64 + B 256x64) bf16 = 128 KiB.
// Stage slots per tile t: q0: B1(t+1)  q1: A0(t+2)  q2: A1(t+1)  q3: B0(t+2)
// Steady-state waits: q0: vmcnt(8), q1: vmcnt(6), q2: -, q3: vmcnt(8);
// tail tiles tighten per guards.  Source-side XOR swizzle (lane l loads
// 16B-group (l&7)^(l>>3) of row c*8+(l>>3); reads invert).
// EPI=1: split store -> out0 bf16 (n<split) / out1 bf16 (n>=split)
// ---------------------------------------------------------------------------
template <int EPI>
__global__ __launch_bounds__(512) void gemm8p(const __bf16* __restrict__ A,
                                              const __bf16* __restrict__ Bb,
                                              int M, int N, int K,
                                              __bf16* __restrict__ out0,
                                              __bf16* __restrict__ out1,
                                              int split) {
    __shared__ __align__(16) __bf16 sA[2][256 * 64];
    __shared__ __align__(16) __bf16 sB[2][256 * 64];
    const int NT = K >> 6;
    int tid = threadIdx.x, w = tid >> 6, lane = tid & 63;
    int wr = w >> 2, wc = w & 3;
    int lr = lane & 15, lq = lane >> 4;
    int srow = lane >> 3;
    int sg = ((lane & 7) ^ srow) * 8;

    // XCD-aware block swizzle (grid = 256, %8 == 0 -> bijective)
    int nbx = N >> 8;
    int cpx = gridDim.x >> 3;
    int wg = (blockIdx.x & 7) * cpx + (blockIdx.x >> 3);
    int by = wg / nbx, bx = wg % nbx;
    int m0 = by * 256, n0 = bx * 256;

    auto stageA = [&](int b, int t, int h) {
        int k0 = t * 64;
#pragma unroll
        for (int l = 0; l < 2; ++l) {
            int c = w * 2 + l;                                   // 0..15
            int base = (c >> 3) * 128 + h * 64 + (c & 7) * 8;    // chunk row base
            const __bf16* g = A + (size_t)(m0 + base + srow) * K + k0 + sg;
            async_cp16(&sA[b][base * 64], g);
        }
    };
    auto stageB = [&](int b, int t, int h) {
        int k0 = t * 64;
#pragma unroll
        for (int l = 0; l < 2; ++l) {
            int c = w * 2 + l;
            int base = (c >> 2) * 64 + h * 32 + (c & 3) * 8;
            const __bf16* g = Bb + (size_t)(n0 + base + srow) * K + k0 + sg;
            async_cp16(&sB[b][base * 64], g);
        }
    };

    floatx4 acc[8][4] = {};

    // Prologue issue order (chronological, matches steady-state ledger):
    // A0(0), B0(0), B1(0), A0(1), A1(0), B0(1)
    stageA(0, 0, 0); stageB(0, 0, 0); stageB(0, 0, 1);
    stageA(1, 1, 0); stageA(0, 0, 1); stageB(1, 1, 0);
    // due: A0(0),B0(0); allowed in flight: B1(0),A0(1),A1(0),B0(1) = 8 loads
    asm volatile("s_waitcnt vmcnt(8)" ::: "memory");
    __builtin_amdgcn_s_barrier();
    __builtin_amdgcn_sched_barrier(0);

    for (int t = 0; t < NT; ++t) {
        int b = t & 1;
        bf16x8 af[8], bfr[4];
#pragma unroll
        for (int q = 0; q < 4; ++q) {
            const int qi = q >> 1, qj = q & 1;
            if (qj == 0) {                                 // A-frags held across 2 phases
#pragma unroll
                for (int i = 0; i < 4; ++i)
#pragma unroll
                    for (int kh = 0; kh < 2; ++kh)
                        af[i * 2 + kh] = *(const bf16x8*)&sA[b][
                            (wr * 128 + qi * 64 + i * 16 + lr) * 64 +
                            (((kh * 4 + lq) ^ (lr & 7)) * 8)];
            }
#pragma unroll
            for (int j = 0; j < 2; ++j)
#pragma unroll
                for (int kh = 0; kh < 2; ++kh)
                    bfr[j * 2 + kh] = *(const bf16x8*)&sB[b][
                        (wc * 64 + (qj * 2 + j) * 16 + lr) * 64 +
                        (((kh * 4 + lq) ^ (lr & 7)) * 8)];

            // stage slot (region freed by prior phases' barriers)
            if      (q == 0) { if (t + 1 < NT) stageB(b ^ 1, t + 1, 1); }
            else if (q == 1) { if (t + 2 < NT) stageA(b,     t + 2, 0); }
            else if (q == 2) { if (t + 1 < NT) stageA(b ^ 1, t + 1, 1); }
            else             { if (t + 2 < NT) stageB(b,     t + 2, 0); }

            __builtin_amdgcn_sched_barrier(0);
            __builtin_amdgcn_s_barrier();
            __builtin_amdgcn_sched_barrier(0);

            __builtin_amdgcn_s_setprio(1);
#pragma unroll
            for (int i = 0; i < 4; ++i)
#pragma unroll
                for (int j = 0; j < 2; ++j)
#pragma unroll
                    for (int kh = 0; kh < 2; ++kh)
                        acc[qi * 4 + i][qj * 2 + j] = __builtin_amdgcn_mfma_f32_16x16x32_bf16(
                            af[i * 2 + kh], bfr[j * 2 + kh], acc[qi * 4 + i][qj * 2 + j], 0, 0, 0);
            __builtin_amdgcn_s_setprio(0);
            __builtin_amdgcn_sched_barrier(0);

            // counted waits (deadline ledger; never 0 in steady state)
            if (q == 0) {
                if (t + 1 < NT) asm volatile("s_waitcnt vmcnt(8)" ::: "memory");
                else            asm volatile("s_waitcnt vmcnt(2)" ::: "memory");
            } else if (q == 1) {
                if      (t + 2 < NT) asm volatile("s_waitcnt vmcnt(6)" ::: "memory");
                else if (t + 1 < NT) asm volatile("s_waitcnt vmcnt(4)" ::: "memory");
                else                 asm volatile("s_waitcnt vmcnt(0)" ::: "memory");
            } else if (q == 3) {
                if      (t + 2 < NT) asm volatile("s_waitcnt vmcnt(8)" ::: "memory");
                else if (t + 1 < NT) asm volatile("s_waitcnt vmcnt(4)" ::: "memory");
            }
            __builtin_amdgcn_s_barrier();
            __builtin_amdgcn_sched_barrier(0);
        }
    }

    // Epilogue: split bf16 store (n < split -> out0, else out1)
#pragma unroll
    for (int i = 0; i < 8; ++i)
#pragma unroll
        for (int j = 0; j < 4; ++j) {
            int gn = n0 + wc * 64 + j * 16 + lr;
#pragma unroll
            for (int r = 0; r < 4; ++r) {
                int gm = m0 + wr * 128 + i * 16 + lq * 4 + r;
                float v = acc[i][j][r];
                if (gn < split) out0[(size_t)gm * split + gn] = (__bf16)v;
                else            out1[(size_t)gm * (N - split) + (gn - split)] = (__bf16)v;
            }
        }
}

// ---------------------------------------------------------------------------
// K2b: GEMM2, T3 minimum-2-phase: double-buffered LDS, next K-tile staged
// BEFORE compute, ONE vmcnt(0)+barrier per K-step.  NW=2: 128x64 tile,
// 512 blocks = 2/CU.  LDS 2x24KB = 48KB.
// EPI=2: residual -> outf fp32 = acc + add[idx]
// ---------------------------------------------------------------------------
template <int EPI, int NW>
__global__ __launch_bounds__(256) void gemm_as(const __bf16* __restrict__ A,
                                               const __bf16* __restrict__ Bb,
                                               int M, int N, int K,
                                               __bf16* __restrict__ out0,
                                               __bf16* __restrict__ out1,
                                               float* __restrict__ outf,
                                               const float* __restrict__ add,
                                               int split) {
    constexpr int BNT = NW * 32;
    constexpr int ACH = 16;                      // A chunks per K-step (128r x 128B)
    constexpr int NCH = ACH + BNT / 8;           // + B chunks
    __shared__ __align__(16) __bf16 sA[2][128 * 64];
    __shared__ __align__(16) __bf16 sB[2][BNT * 64];
    int tid  = threadIdx.x;
    int wave = tid >> 6, lane = tid & 63;
    int m0 = blockIdx.y * 128, n0 = blockIdx.x * BNT;
    int wm = (wave & 1) * 64, wn = (wave >> 1) * (NW * 16);
    int lr = lane & 15;
    int lq = lane >> 4;
    int srow = lane >> 3;                        // row within a chunk (0..7)
    int sg   = ((lane & 7) ^ srow) * 8;          // swizzled source elem group

    auto stage = [&](int b, int k0) {
        for (int c = wave; c < NCH; c += 4) {
            if (c < ACH) {
                const __bf16* g = A + (size_t)(m0 + c * 8 + srow) * K + k0 + sg;
                async_cp16(&sA[b][c * 512], g);
            } else {
                int cb = c - ACH;
                const __bf16* g = Bb + (size_t)(n0 + cb * 8 + srow) * K + k0 + sg;
                async_cp16(&sB[b][cb * 512], g);
            }
        }
    };

    floatx4 acc[4][NW] = {};

    stage(0, 0);
    __builtin_amdgcn_sched_barrier(0);
    asm volatile("s_waitcnt vmcnt(0)" ::: "memory");
    __builtin_amdgcn_s_barrier();
    __builtin_amdgcn_sched_barrier(0);

    int cur = 0;
    for (int k0 = 0; k0 < K; k0 += 64) {
        if (k0 + 64 < K) stage(cur ^ 1, k0 + 64);   // prefetch overlaps compute

#pragma unroll
        for (int s = 0; s < 2; ++s) {
            bf16x8 af[4], bfr[NW];
#pragma unroll
            for (int i = 0; i < 4; ++i) {
                int row = wm + i * 16 + lr;
                af[i] = *(const bf16x8*)&sA[cur][row * 64 + (((s * 4 + lq) ^ (lr & 7)) * 8)];
            }
#pragma unroll
            for (int j = 0; j < NW; ++j) {
                int row = wn + j * 16 + lr;
                bfr[j] = *(const bf16x8*)&sB[cur][row * 64 + (((s * 4 + lq) ^ (lr & 7)) * 8)];
            }
#pragma unroll
            for (int i = 0; i < 4; ++i)
#pragma unroll
                for (int j = 0; j < NW; ++j)
                    acc[i][j] = __builtin_amdgcn_mfma_f32_16x16x32_bf16(af[i], bfr[j], acc[i][j], 0, 0, 0);
        }

        __builtin_amdgcn_sched_barrier(0);
        asm volatile("s_waitcnt vmcnt(0)" ::: "memory");
        __builtin_amdgcn_s_barrier();
        __builtin_amdgcn_sched_barrier(0);
        cur ^= 1;
    }

#pragma unroll
    for (int i = 0; i < 4; ++i)
#pragma unroll
        for (int j = 0; j < NW; ++j) {
            int gn = n0 + wn + j * 16 + lr;
#pragma unroll
            for (int r = 0; r < 4; ++r) {
                int gm = m0 + wm + i * 16 + lq * 4 + r;
                float v = acc[i][j][r];
                if (EPI == 1) {
                    if (gn < split) out0[(size_t)gm * split + gn] = (__bf16)v;
                    else            out1[(size_t)gm * split + (gn - split)] = (__bf16)v;
                } else {
                    size_t idx = (size_t)gm * N + gn;
                    outf[idx] = v + add[idx];
                }
            }
        }
}

// ---------------------------------------------------------------------------
// K3: depthwise causal conv (width 4) + bias + SiLU.  short8-vectorized:
// thread = 8 consecutive channels of one (b,l) row; 4 bf16x8 row loads.
// ---------------------------------------------------------------------------
__global__ __launch_bounds__(256) void conv_kernel(const __bf16* __restrict__ xin,
                                                   const float* __restrict__ cw,
                                                   const float* __restrict__ cb,
                                                   __bf16* __restrict__ u) {
    int t8 = blockIdx.x * 256 + threadIdx.x;         // over MROWS*DINNER/8
    int dg = t8 & (DINNER / 8 - 1);
    int bl = t8 >> 8;                                // b*SEQ + l
    int l  = bl & (SEQ - 1);
    int d0 = dg * 8;
    float acc[8];
#pragma unroll
    for (int k = 0; k < 8; ++k) acc[k] = cb[d0 + k];
    float wgt[8][4];
#pragma unroll
    for (int k = 0; k < 8; ++k) {
        floatx4 wv = *(const floatx4*)&cw[(d0 + k) * 4];
#pragma unroll
        for (int j = 0; j < 4; ++j) wgt[k][j] = wv[j];
    }
#pragma unroll
    for (int j = 0; j < 4; ++j) {
        int ll = l - 3 + j;
        if (ll >= 0) {
            bf16x8 v = *(const bf16x8*)&xin[(size_t)(bl - 3 + j) * DINNER + d0];
#pragma unroll
            for (int k = 0; k < 8; ++k) acc[k] += (float)v[k] * wgt[k][j];
        }
    }
    __bf16 r[8];
#pragma unroll
    for (int k = 0; k < 8; ++k) {
        float sg = 1.f / (1.f + __expf(-acc[k]));
        r[k] = (__bf16)(acc[k] * sg);
    }
    *(bf16x8*)&u[(size_t)bl * DINNER + d0] = *(bf16x8*)r;
}

// ---------------------------------------------------------------------------
// K4 (MFMA, split-K): P[ks][4096,96] = u[4096,2048](K-slice ks) @ Wx^T.
// Partial STORES (no atomics).  WX_KS=8 -> partials 12 MiB.  wx_reduce sums.
// ---------------------------------------------------------------------------
#define BM 128
#define BN 128
#define BK 32
#define LDK 48
#define WX_KS 8
#define WX_KSLICE (DINNER / WX_KS)   // 256

__global__ __launch_bounds__(256) void wx_mfma(const __bf16* __restrict__ A,
                                               const float* __restrict__ B,
                                               float* __restrict__ P) {
    __shared__ __align__(16) __bf16 sA[BM][LDK];
    __shared__ __align__(16) __bf16 sB[96][LDK];
    int tid  = threadIdx.x;
    int wave = tid >> 6, lane = tid & 63;
    int m0 = blockIdx.x * BM;
    int k0base = blockIdx.y * WX_KSLICE;
    int wm = (wave & 1) * 64, wn = (wave >> 1) * 48;
    int lr = lane & 15;
    int lq = lane >> 4;

    floatx4 acc[4][3] = {};

    for (int k0 = k0base; k0 < k0base + WX_KSLICE; k0 += BK) {
#pragma unroll
        for (int c = tid; c < 512; c += 256) {
            int row = c >> 2, col = (c & 3) * 8;
            *(bf16x8*)&sA[row][col] = *(const bf16x8*)&A[(size_t)(m0 + row) * DINNER + k0 + col];
        }
        for (int c = tid; c < 384; c += 256) {
            int row = c >> 2, col = (c & 3) * 8;
            const float* src = B + (size_t)row * DINNER + k0 + col;
            floatx4 lo = *(const floatx4*)src;
            floatx4 hi = *(const floatx4*)(src + 4);
            bf16x8 v;
#pragma unroll
            for (int t = 0; t < 4; ++t) { v[t] = (__bf16)lo[t]; v[4 + t] = (__bf16)hi[t]; }
            *(bf16x8*)&sB[row][col] = v;
        }
        __syncthreads();

        bf16x8 af[4], bfr[3];
#pragma unroll
        for (int i = 0; i < 4; ++i) af[i]  = *(const bf16x8*)&sA[wm + i * 16 + lr][lq * 8];
#pragma unroll
        for (int j = 0; j < 3; ++j) bfr[j] = *(const bf16x8*)&sB[wn + j * 16 + lr][lq * 8];
#pragma unroll
        for (int i = 0; i < 4; ++i)
#pragma unroll
            for (int j = 0; j < 3; ++j)
                acc[i][j] = __builtin_amdgcn_mfma_f32_16x16x32_bf16(af[i], bfr[j], acc[i][j], 0, 0, 0);
        __syncthreads();
    }

    float* Pk = P + (size_t)blockIdx.y * (MROWS * 96);
#pragma unroll
    for (int i = 0; i < 4; ++i)
#pragma unroll
        for (int j = 0; j < 3; ++j) {
            int gn = wn + j * 16 + lr;
#pragma unroll
            for (int r = 0; r < 4; ++r) {
                int gm = m0 + wm + i * 16 + lq * 4 + r;
                Pk[(size_t)gm * 96 + gn] = acc[i][j][r];
            }
        }
}

__global__ __launch_bounds__(256) void wx_reduce(const float* __restrict__ P,
                                                 float* __restrict__ xdbl) {
    int i = (blockIdx.x * 256 + threadIdx.x) * 4;    // over MROWS*96
    floatx4 s = *(const floatx4*)&P[i];
#pragma unroll
    for (int k = 1; k < WX_KS; ++k) {
        floatx4 v = *(const floatx4*)&P[(size_t)k * (MROWS * 96) + i];
        s += v;
    }
    *(floatx4*)&xdbl[i] = s;
}

// ---------------------------------------------------------------------------
// K5 (MFMA): dt[4096,2048] = softplus(xdbl[:,0:64] @ Wdt[2048,64]^T + b_dt)
// ---------------------------------------------------------------------------
__global__ __launch_bounds__(256) void dt_mfma(const float* __restrict__ Af,
                                               const float* __restrict__ B,
                                               const float* __restrict__ bdt,
                                               __bf16* __restrict__ dt) {
    __shared__ __align__(16) __bf16 sA[BM][LDK];
    __shared__ __align__(16) __bf16 sB[BN][LDK];
    int tid  = threadIdx.x;
    int wave = tid >> 6, lane = tid & 63;
    int m0 = blockIdx.y * BM, n0 = blockIdx.x * BN;
    int wm = (wave & 1) * 64, wn = (wave >> 1) * 64;
    int lr = lane & 15;
    int lq = lane >> 4;

    floatx4 acc[4][4] = {};

    for (int k0 = 0; k0 < DTRANK; k0 += BK) {
#pragma unroll
        for (int c = tid; c < 512; c += 256) {
            int row = c >> 2, col = (c & 3) * 8;
            const float* src = Af + (size_t)(m0 + row) * 96 + k0 + col;
            floatx4 lo = *(const floatx4*)src;
            floatx4 hi = *(const floatx4*)(src + 4);
            bf16x8 v;
#pragma unroll
            for (int t = 0; t < 4; ++t) { v[t] = (__bf16)lo[t]; v[4 + t] = (__bf16)hi[t]; }
            *(bf16x8*)&sA[row][col] = v;
        }
#pragma unroll
        for (int c = tid; c < 512; c += 256) {
            int row = c >> 2, col = (c & 3) * 8;
            const float* src = B + (size_t)(n0 + row) * DTRANK + k0 + col;
            floatx4 lo = *(const floatx4*)src;
            floatx4 hi = *(const floatx4*)(src + 4);
            bf16x8 v;
#pragma unroll
            for (int t = 0; t < 4; ++t) { v[t] = (__bf16)lo[t]; v[4 + t] = (__bf16)hi[t]; }
            *(bf16x8*)&sB[row][col] = v;
        }
        __syncthreads();

        bf16x8 af[4], bfr[4];
#pragma unroll
        for (int i = 0; i < 4; ++i) af[i]  = *(const bf16x8*)&sA[wm + i * 16 + lr][lq * 8];
#pragma unroll
        for (int j = 0; j < 4; ++j) bfr[j] = *(const bf16x8*)&sB[wn + j * 16 + lr][lq * 8];
#pragma unroll
        for (int i = 0; i < 4; ++i)
#pragma unroll
            for (int j = 0; j < 4; ++j)
                acc[i][j] = __builtin_amdgcn_mfma_f32_16x16x32_bf16(af[i], bfr[j], acc[i][j], 0, 0, 0);
        __syncthreads();
    }

#pragma unroll
    for (int i = 0; i < 4; ++i)
#pragma unroll
        for (int j = 0; j < 4; ++j) {
            int gn = n0 + wn + j * 16 + lr;
            float bv = bdt[gn];
#pragma unroll
            for (int r = 0; r < 4; ++r) {
                int gm = m0 + wm + i * 16 + lq * 4 + r;
                float a = acc[i][j][r] + bv;
                float sp = (a > 20.f) ? a : log1pf(__expf(a));
                dt[(size_t)gm * DINNER + gn] = (__bf16)sp;
            }
        }
}

// ---------------------------------------------------------------------------
// K6 (3-pass chunked scan), LDS-free.  Wave = 64 consecutive channels
// (coalesced dt/u/z loads, uniform B/C -> s_load), 16 states/lane.
// R20-proven depth-1 rotation (t+1 loads issued before t's chain).
// R22: CLEN=32 -> 4096 waves (16/CU) for latency hiding.
// ---------------------------------------------------------------------------
__global__ __launch_bounds__(64) void scan_pass1(const __bf16* __restrict__ dt,
                                                 const __bf16* __restrict__ u,
                                                 const float* __restrict__ xdbl,
                                                 const float* __restrict__ Alog,
                                                 float* __restrict__ Sdt,
                                                 __bf16* __restrict__ Hfix) {
    int c = blockIdx.x, dblk = blockIdx.y, b = blockIdx.z;
    int lane = threadIdx.x;
    int d = dblk * 64 + lane;
    int row0 = b * SEQ + c * CLEN;

    const __bf16* dtp = dt + (size_t)row0 * DINNER + d;
    const __bf16* up  = u  + (size_t)row0 * DINNER + d;
    const float*  bcp = xdbl + (size_t)row0 * 96 + 64;

    float A[DSTATE], h[DSTATE];
#pragma unroll
    for (int s = 0; s < DSTATE; ++s) { A[s] = -__expf(Alog[d * DSTATE + s]); h[s] = 0.f; }

    float S = 0.f;
    // prefetch t=0
    float dtv_n = (float)dtp[0];
    float uv_n  = (float)up[0];
    floatx4 B0n = *(const floatx4*)(bcp);
    floatx4 B1n = *(const floatx4*)(bcp + 4);
    floatx4 B2n = *(const floatx4*)(bcp + 8);
    floatx4 B3n = *(const floatx4*)(bcp + 12);
    for (int t = 0; t < CLEN; ++t) {
        float dtv = dtv_n, uv = uv_n;
        floatx4 B0 = B0n, B1 = B1n, B2 = B2n, B3 = B3n;
        if (t + 1 < CLEN) {                 // issue t+1 loads before t's chain
            dtv_n = (float)dtp[(size_t)(t + 1) * DINNER];
            uv_n  = (float)up [(size_t)(t + 1) * DINNER];
            B0n = *(const floatx4*)(bcp + (t + 1) * 96);
            B1n = *(const floatx4*)(bcp + (t + 1) * 96 + 4);
            B2n = *(const floatx4*)(bcp + (t + 1) * 96 + 8);
            B3n = *(const floatx4*)(bcp + (t + 1) * 96 + 12);
        }
        S += dtv;
        float du = dtv * uv;
#pragma unroll
        for (int s = 0; s < 4; ++s) {
            h[s]      = __expf(dtv * A[s])      * h[s]      + du * B0[s];
            h[4 + s]  = __expf(dtv * A[4 + s])  * h[4 + s]  + du * B1[s];
            h[8 + s]  = __expf(dtv * A[8 + s])  * h[8 + s]  + du * B2[s];
            h[12 + s] = __expf(dtv * A[12 + s]) * h[12 + s] + du * B3[s];
        }
    }
    size_t ch = ((size_t)(b * DINNER + d) * CHUNKS + c);
    Sdt[ch] = S;
#pragma unroll
    for (int s = 0; s < DSTATE; ++s) Hfix[ch * DSTATE + s] = (__bf16)h[s];
}

__global__ __launch_bounds__(256) void scan_pass2(const float* __restrict__ Alog,
                                                  const float* __restrict__ Sdt,
                                                  __bf16* __restrict__ Hfix) {
    int g = blockIdx.x * 256 + threadIdx.x;       // over BATCH*DINNER*DSTATE
    int s = g & (DSTATE - 1);
    int bd = g >> 4;
    int d = bd & (DINNER - 1);
    float A = -__expf(Alog[d * DSTATE + s]);
    size_t hbase = (size_t)bd * CHUNKS * DSTATE + s;
    size_t sbase = (size_t)bd * CHUNKS;
    float h = 0.f;
#pragma unroll 4
    for (int c = 0; c < CHUNKS; ++c) {
        float Hl = (float)Hfix[hbase + c * DSTATE];
        float P  = __expf(A * Sdt[sbase + c]);
        Hfix[hbase + c * DSTATE] = (__bf16)h;
        h = P * h + Hl;
    }
}

__global__ __launch_bounds__(64) void scan_pass3(const __bf16* __restrict__ dt,
                                                 const __bf16* __restrict__ u,
                                                 const float* __restrict__ xdbl,
                                                 const float* __restrict__ Alog,
                                                 const float* __restrict__ Dp,
                                                 const __bf16* __restrict__ Hfix,
                                                 __bf16* zy) {
    int c = blockIdx.x, dblk = blockIdx.y, b = blockIdx.z;
    int lane = threadIdx.x;
    int d = dblk * 64 + lane;
    int row0 = b * SEQ + c * CLEN;

    const __bf16* dtp = dt + (size_t)row0 * DINNER + d;
    const __bf16* up  = u  + (size_t)row0 * DINNER + d;
    __bf16*       zyp = zy + (size_t)row0 * DINNER + d;
    const float*  bcp = xdbl + (size_t)row0 * 96 + 64;

    float A[DSTATE], h[DSTATE];
    size_t ch = ((size_t)(b * DINNER + d) * CHUNKS + c);
#pragma unroll
    for (int s = 0; s < DSTATE; ++s) {
        A[s] = -__expf(Alog[d * DSTATE + s]);
        h[s] = (float)Hfix[ch * DSTATE + s];
    }
    float Dv = Dp[d];

    // prefetch t=0
    float dtv_n = (float)dtp[0];
    float uv_n  = (float)up[0];
    float zv_n  = (float)zyp[0];
    floatx4 B0n = *(const floatx4*)(bcp);
    floatx4 B1n = *(const floatx4*)(bcp + 4);
    floatx4 B2n = *(const floatx4*)(bcp + 8);
    floatx4 B3n = *(const floatx4*)(bcp + 12);
    floatx4 C0n = *(const floatx4*)(bcp + 16);
    floatx4 C1n = *(const floatx4*)(bcp + 20);
    floatx4 C2n = *(const floatx4*)(bcp + 24);
    floatx4 C3n = *(const floatx4*)(bcp + 28);
    for (int t = 0; t < CLEN; ++t) {
        float dtv = dtv_n, uv = uv_n, zv = zv_n;
        floatx4 B0 = B0n, B1 = B1n, B2 = B2n, B3 = B3n;
        floatx4 C0 = C0n, C1 = C1n, C2 = C2n, C3 = C3n;
        if (t + 1 < CLEN) {                 // issue t+1 loads before t's chain
            dtv_n = (float)dtp[(size_t)(t + 1) * DINNER];
            uv_n  = (float)up [(size_t)(t + 1) * DINNER];
            zv_n  = (float)zyp[(size_t)(t + 1) * DINNER];
            B0n = *(const floatx4*)(bcp + (t + 1) * 96);
            B1n = *(const floatx4*)(bcp + (t + 1) * 96 + 4);
            B2n = *(const floatx4*)(bcp + (t + 1) * 96 + 8);
            B3n = *(const floatx4*)(bcp + (t + 1) * 96 + 12);
            C0n = *(const floatx4*)(bcp + (t + 1) * 96 + 16);
            C1n = *(const floatx4*)(bcp + (t + 1) * 96 + 20);
            C2n = *(const floatx4*)(bcp + (t + 1) * 96 + 24);
            C3n = *(const floatx4*)(bcp + (t + 1) * 96 + 28);
        }
        float du = dtv * uv;
        float yv = 0.f;
#pragma unroll
        for (int s = 0; s < 4; ++s) {
            h[s]      = __expf(dtv * A[s])      * h[s]      + du * B0[s];
            h[4 + s]  = __expf(dtv * A[4 + s])  * h[4 + s]  + du * B1[s];
            h[8 + s]  = __expf(dtv * A[8 + s])  * h[8 + s]  + du * B2[s];
            h[12 + s] = __expf(dtv * A[12 + s]) * h[12 + s] + du * B3[s];
            yv += h[s] * C0[s] + h[4 + s] * C1[s] + h[8 + s] * C2[s] + h[12 + s] * C3[s];
        }
        float sg = zv / (1.f + __expf(-zv));
        zyp[(size_t)t * DINNER] = (__bf16)((yv + uv * Dv) * sg);
    }
}

// ---------------------------------------------------------------------------
extern "C" void kernel_launch(void* const* d_in, const int* in_sizes, int n_in,
                              void* d_out, int out_size, void* d_ws, size_t ws_size,
                              hipStream_t stream) {
    const float* x      = (const float*)d_in[0];
    const float* ln_w   = (const float*)d_in[1];
    const float* ln_b   = (const float*)d_in[2];
    const float* W_in   = (const float*)d_in[3];
    const float* conv_w = (const float*)d_in[4];
    const float* conv_b = (const float*)d_in[5];
    const float* W_x    = (const float*)d_in[6];
    const float* W_dt   = (const float*)d_in[7];
    const float* b_dt   = (const float*)d_in[8];
    const float* A_log  = (const float*)d_in[9];
    const float* Dp     = (const float*)d_in[10];
    const float* W_out  = (const float*)d_in[11];
    float* out = (float*)d_out;

    // Workspace, 56 MiB peak:
    //   [ 0,  8M)  xn bf16 (dead after GEMM1) -> { xdbl fp32 [0,1.5M),
    //              Sdt fp32 [1.5M,2.5M) }
    //   [ 8M,24M)  x_in bf16 (dead after conv) -> wxP fp32 12M (wx..reduce)
    //              -> dt bf16 (dt_mfma..pass3)
    //   [24M,40M)  z bf16; scan pass3 overwrites with y in place
    //   [40M,56M)  Winb bf16 8M (dead after GEMM1) -> u bf16 16M (conv..pass3)
    //              -> Woutb bf16 4M (after pass3)
    //   Hfix bf16 8.4M lives in d_out (dead until final GEMM2 overwrites it).
    char* ws = (char*)d_ws;
    __bf16* xn_bf  = (__bf16*)(ws);
    float*  xdbl   = (float*) (ws);
    float*  Sdt    = (float*) (ws + 1536ull * 1024);
    __bf16* Hfix   = (__bf16*)(d_out);
    __bf16* xin_bf = (__bf16*)(ws + (8ull  << 20));
    float*  wxP    = (float*) (ws + (8ull  << 20));
    __bf16* dt_bf  = (__bf16*)(ws + (8ull  << 20));
    __bf16* zy_bf  = (__bf16*)(ws + (24ull << 20));
    __bf16* Winb   = (__bf16*)(ws + (40ull << 20));
    __bf16* u_bf   = (__bf16*)(ws + (40ull << 20));
    __bf16* Woutb  = (__bf16*)(ws + (40ull << 20));

    ln_kernel<<<MROWS, 256, 0, stream>>>(x, ln_w, ln_b, xn_bf);

    w2bf<<<(2 * DINNER * DMODEL) / 1024, 256, 0, stream>>>(W_in, Winb, 2 * DINNER * DMODEL);

    // GEMM1: 8-phase 256x256 template, grid = 16x16 = 256 blocks (1/CU)
    gemm8p<1><<<(MROWS / 256) * (2 * DINNER / 256), 512, 0, stream>>>(
        xn_bf, Winb, MROWS, 2 * DINNER, DMODEL, xin_bf, zy_bf, DINNER);

    conv_kernel<<<MROWS * DINNER / (8 * 256), 256, 0, stream>>>(xin_bf, conv_w, conv_b, u_bf);

    // wx: split-K partial stores (no atomics, no memset), then reduce
    wx_mfma<<<dim3(MROWS / BM, WX_KS), 256, 0, stream>>>(u_bf, W_x, wxP);
    wx_reduce<<<(MROWS * 96) / 1024, 256, 0, stream>>>(wxP, xdbl);

    dt_mfma<<<dim3(DINNER / BN, MROWS / BM), 256, 0, stream>>>(xdbl, W_dt, b_dt, dt_bf);

    dim3 sgrid(CHUNKS, DINNER / 64, BATCH);
    scan_pass1<<<sgrid, 64, 0, stream>>>(dt_bf, u_bf, xdbl, A_log, Sdt, Hfix);
    scan_pass2<<<BATCH * DINNER * DSTATE / 256, 256, 0, stream>>>(A_log, Sdt, Hfix);
    scan_pass3<<<sgrid, 64, 0, stream>>>(dt_bf, u_bf, xdbl, A_log, Dp, Hfix, zy_bf);

    w2bf<<<(DMODEL * DINNER) / 1024, 256, 0, stream>>>(W_out, Woutb, DMODEL * DINNER);

    // GEMM2: gemm_as NW=2 double-buffered prefetch (512 blocks = 2/CU);
    // fully overwrites d_out (incl. the Hfix scratch region).
    gemm_as<2, 2><<<dim3(DMODEL / 64, MROWS / 128), 256, 0, stream>>>(
        zy_bf, Woutb, MROWS, DMODEL, DINNER, nullptr, nullptr, out, x, 0);
}

// Round 12
// 333.243 us; speedup vs baseline: 1.1550x; 1.0113x over previous
//
#include <hip/hip_runtime.h>

// ---------------------------------------------------------------------------
// Mamba block. fp32 in/out. Internal: bf16 MFMA operands, fp32 accumulation
// and scan state.
// R23 (from best R22 @ 337us): GEMM1 epilogue rework. Was 128 scattered
// 2B global_store_short per thread (4x32B segments per wave-inst, ~8-12us
// serial tail). Now: accumulator round-trips through LDS (per-wave 16KB
// region of the freed 128KB staging space; no cross-wave sync needed) and
// stores as bf16x8 16B/lane -> 8x128B contiguous segments per inst, 16
// insts/thread. out0/out1 target is block-uniform (split is 256-aligned).
// All else identical to R22 (8-phase gemm8p K-loop, 2-phase gemm_as<2,2>
// GEMM2, conv short8, wx partial+reduce, CLEN=32 scans, Hfix in d_out).
// ---------------------------------------------------------------------------
#define BATCH   2
#define SEQ     2048
#define DMODEL  1024
#define DINNER  2048
#define DSTATE  16
#define DTRANK  64
#define MROWS   (BATCH * SEQ)   // 4096
#define CLEN    32              // scan chunk length
#define CHUNKS  (SEQ / CLEN)    // 64

typedef float floatx4 __attribute__((ext_vector_type(4)));
typedef __bf16 bf16x8 __attribute__((ext_vector_type(8)));

__device__ __forceinline__ void async_cp16(void* lds, const void* g) {
    __builtin_amdgcn_global_load_lds((const __attribute__((address_space(1))) void*)g,
                                     (__attribute__((address_space(3))) void*)lds, 16, 0, 0);
}

// ---------------------------------------------------------------------------
// K0: fp32 -> bf16 weight conversion
// ---------------------------------------------------------------------------
__global__ __launch_bounds__(256) void w2bf(const float* __restrict__ w,
                                            __bf16* __restrict__ o, int n) {
    int i = (blockIdx.x * 256 + threadIdx.x) * 4;
    if (i < n) {
        floatx4 v = *(const floatx4*)&w[i];
        __bf16 r[4];
#pragma unroll
        for (int t = 0; t < 4; ++t) r[t] = (__bf16)v[t];
        *(unsigned long long*)&o[i] = *(unsigned long long*)r;
    }
}

// ---------------------------------------------------------------------------
// K1: LayerNorm.  One block per row of 1024.  fp32 in, bf16 out (GEMM A-op).
// ---------------------------------------------------------------------------
__global__ __launch_bounds__(256) void ln_kernel(const float* __restrict__ x,
                                                 const float* __restrict__ w,
                                                 const float* __restrict__ b,
                                                 __bf16* __restrict__ xn) {
    int row = blockIdx.x;
    const float* xr = x + (size_t)row * DMODEL;
    float v[4], s = 0.f, ss = 0.f;
#pragma unroll
    for (int i = 0; i < 4; ++i) {
        v[i] = xr[threadIdx.x + i * 256];
        s += v[i]; ss += v[i] * v[i];
    }
#pragma unroll
    for (int o = 32; o > 0; o >>= 1) { s += __shfl_xor(s, o); ss += __shfl_xor(ss, o); }
    __shared__ float ps[4], pss[4];
    int wv = threadIdx.x >> 6;
    if ((threadIdx.x & 63) == 0) { ps[wv] = s; pss[wv] = ss; }
    __syncthreads();
    s  = ps[0] + ps[1] + ps[2] + ps[3];
    ss = pss[0] + pss[1] + pss[2] + pss[3];
    float mu  = s * (1.f / DMODEL);
    float var = ss * (1.f / DMODEL) - mu * mu;
    float rs  = rsqrtf(var + 1e-5f);
#pragma unroll
    for (int i = 0; i < 4; ++i) {
        int c = threadIdx.x + i * 256;
        xn[(size_t)row * DMODEL + c] = (__bf16)((v[i] - mu) * rs * w[c] + b[c]);
    }
}

// ---------------------------------------------------------------------------
// K2a: 8-phase 256x256 GEMM (GEMM1).  C[M,N] = A[M,K] * B[N,K]^T, bf16 in.
// 512 thr = 8 waves (2M x 4N); wave owns 128x64 of C (acc[8][4]).
// LDS: 2 K-tile buffers x (A 256x64 + B 256x64) bf16 = 128 KiB.
// Stage slots per tile t: q0: B1(t+1)  q1: A0(t+2)  q2: A1(t+1)  q3: B0(t+2)
// Steady-state waits: q0: vmcnt(8), q1: vmcnt(6), q2: -, q3: vmcnt(8);
// tail tiles tighten per guards.  Source-side XOR swizzle (lane l loads
// 16B-group (l&7)^(l>>3) of row c*8+(l>>3); reads invert).
// Epilogue (R23): acc -> bf16 into per-wave 16KB LDS region (row-major
// 128x64), same-wave readback as bf16x8, 16B/lane coalesced stores.
// EPI=1: split store -> out0 bf16 (n<split) / out1 bf16 (n>=split);
// split is 256-aligned so the target is block-uniform.
// ---------------------------------------------------------------------------
template <int EPI>
__global__ __launch_bounds__(512) void gemm8p(const __bf16* __restrict__ A,
                                              const __bf16* __restrict__ Bb,
                                              int M, int N, int K,
                                              __bf16* __restrict__ out0,
                                              __bf16* __restrict__ out1,
                                              int split) {
    __shared__ __align__(16) __bf16 sA[2][256 * 64];
    __shared__ __align__(16) __bf16 sB[2][256 * 64];
    const int NT = K >> 6;
    int tid = threadIdx.x, w = tid >> 6, lane = tid & 63;
    int wr = w >> 2, wc = w & 3;
    int lr = lane & 15, lq = lane >> 4;
    int srow = lane >> 3;
    int sg = ((lane & 7) ^ srow) * 8;

    // XCD-aware block swizzle (grid = 256, %8 == 0 -> bijective)
    int nbx = N >> 8;
    int cpx = gridDim.x >> 3;
    int wg = (blockIdx.x & 7) * cpx + (blockIdx.x >> 3);
    int by = wg / nbx, bx = wg % nbx;
    int m0 = by * 256, n0 = bx * 256;

    auto stageA = [&](int b, int t, int h) {
        int k0 = t * 64;
#pragma unroll
        for (int l = 0; l < 2; ++l) {
            int c = w * 2 + l;                                   // 0..15
            int base = (c >> 3) * 128 + h * 64 + (c & 7) * 8;    // chunk row base
            const __bf16* g = A + (size_t)(m0 + base + srow) * K + k0 + sg;
            async_cp16(&sA[b][base * 64], g);
        }
    };
    auto stageB = [&](int b, int t, int h) {
        int k0 = t * 64;
#pragma unroll
        for (int l = 0; l < 2; ++l) {
            int c = w * 2 + l;
            int base = (c >> 2) * 64 + h * 32 + (c & 3) * 8;
            const __bf16* g = Bb + (size_t)(n0 + base + srow) * K + k0 + sg;
            async_cp16(&sB[b][base * 64], g);
        }
    };

    floatx4 acc[8][4] = {};

    // Prologue issue order (chronological, matches steady-state ledger):
    // A0(0), B0(0), B1(0), A0(1), A1(0), B0(1)
    stageA(0, 0, 0); stageB(0, 0, 0); stageB(0, 0, 1);
    stageA(1, 1, 0); stageA(0, 0, 1); stageB(1, 1, 0);
    // due: A0(0),B0(0); allowed in flight: B1(0),A0(1),A1(0),B0(1) = 8 loads
    asm volatile("s_waitcnt vmcnt(8)" ::: "memory");
    __builtin_amdgcn_s_barrier();
    __builtin_amdgcn_sched_barrier(0);

    for (int t = 0; t < NT; ++t) {
        int b = t & 1;
        bf16x8 af[8], bfr[4];
#pragma unroll
        for (int q = 0; q < 4; ++q) {
            const int qi = q >> 1, qj = q & 1;
            if (qj == 0) {                                 // A-frags held across 2 phases
#pragma unroll
                for (int i = 0; i < 4; ++i)
#pragma unroll
                    for (int kh = 0; kh < 2; ++kh)
                        af[i * 2 + kh] = *(const bf16x8*)&sA[b][
                            (wr * 128 + qi * 64 + i * 16 + lr) * 64 +
                            (((kh * 4 + lq) ^ (lr & 7)) * 8)];
            }
#pragma unroll
            for (int j = 0; j < 2; ++j)
#pragma unroll
                for (int kh = 0; kh < 2; ++kh)
                    bfr[j * 2 + kh] = *(const bf16x8*)&sB[b][
                        (wc * 64 + (qj * 2 + j) * 16 + lr) * 64 +
                        (((kh * 4 + lq) ^ (lr & 7)) * 8)];

            // stage slot (region freed by prior phases' barriers)
            if      (q == 0) { if (t + 1 < NT) stageB(b ^ 1, t + 1, 1); }
            else if (q == 1) { if (t + 2 < NT) stageA(b,     t + 2, 0); }
            else if (q == 2) { if (t + 1 < NT) stageA(b ^ 1, t + 1, 1); }
            else             { if (t + 2 < NT) stageB(b,     t + 2, 0); }

            __builtin_amdgcn_sched_barrier(0);
            __builtin_amdgcn_s_barrier();
            __builtin_amdgcn_sched_barrier(0);

            __builtin_amdgcn_s_setprio(1);
#pragma unroll
            for (int i = 0; i < 4; ++i)
#pragma unroll
                for (int j = 0; j < 2; ++j)
#pragma unroll
                    for (int kh = 0; kh < 2; ++kh)
                        acc[qi * 4 + i][qj * 2 + j] = __builtin_amdgcn_mfma_f32_16x16x32_bf16(
                            af[i * 2 + kh], bfr[j * 2 + kh], acc[qi * 4 + i][qj * 2 + j], 0, 0, 0);
            __builtin_amdgcn_s_setprio(0);
            __builtin_amdgcn_sched_barrier(0);

            // counted waits (deadline ledger; never 0 in steady state)
            if (q == 0) {
                if (t + 1 < NT) asm volatile("s_waitcnt vmcnt(8)" ::: "memory");
                else            asm volatile("s_waitcnt vmcnt(2)" ::: "memory");
            } else if (q == 1) {
                if      (t + 2 < NT) asm volatile("s_waitcnt vmcnt(6)" ::: "memory");
                else if (t + 1 < NT) asm volatile("s_waitcnt vmcnt(4)" ::: "memory");
                else                 asm volatile("s_waitcnt vmcnt(0)" ::: "memory");
            } else if (q == 3) {
                if      (t + 2 < NT) asm volatile("s_waitcnt vmcnt(8)" ::: "memory");
                else if (t + 1 < NT) asm volatile("s_waitcnt vmcnt(4)" ::: "memory");
            }
            __builtin_amdgcn_s_barrier();
            __builtin_amdgcn_sched_barrier(0);
        }
    }

    // Epilogue (R23): LDS round-trip for coalesced 16B stores.
    // Each wave owns a private 16KB region (8 waves = the full 128KB);
    // same-wave ds_write -> ds_read needs only lgkmcnt (compiler-inserted).
    __bf16* ep = (w < 4) ? &sA[0][0] + w * 8192 : &sB[0][0] + (w - 4) * 8192;
#pragma unroll
    for (int i = 0; i < 8; ++i)
#pragma unroll
        for (int j = 0; j < 4; ++j)
#pragma unroll
            for (int r = 0; r < 4; ++r)
                ep[(i * 16 + lq * 4 + r) * 64 + j * 16 + lr] = (__bf16)acc[i][j][r];

    __bf16* outp; size_t ostr; int ocol;
    if (n0 < split) { outp = out0; ostr = split;     ocol = n0 + wc * 64; }
    else            { outp = out1; ostr = N - split; ocol = n0 - split + wc * 64; }
    int lrow0 = lane >> 3, lcol0 = (lane & 7) * 8;
#pragma unroll
    for (int rr = 0; rr < 16; ++rr) {
        bf16x8 v = *(const bf16x8*)&ep[(rr * 8 + lrow0) * 64 + lcol0];
        int gm = m0 + wr * 128 + rr * 8 + lrow0;
        *(bf16x8*)&outp[(size_t)gm * ostr + ocol + lcol0] = v;
    }
}

// ---------------------------------------------------------------------------
// K2b: GEMM2, T3 minimum-2-phase: double-buffered LDS, next K-tile staged
// BEFORE compute, ONE vmcnt(0)+barrier per K-step.  NW=2: 128x64 tile,
// 512 blocks = 2/CU.  LDS 2x24KB = 48KB.
// EPI=2: residual -> outf fp32 = acc + add[idx]
// ---------------------------------------------------------------------------
template <int EPI, int NW>
__global__ __launch_bounds__(256) void gemm_as(const __bf16* __restrict__ A,
                                               const __bf16* __restrict__ Bb,
                                               int M, int N, int K,
                                               __bf16* __restrict__ out0,
                                               __bf16* __restrict__ out1,
                                               float* __restrict__ outf,
                                               const float* __restrict__ add,
                                               int split) {
    constexpr int BNT = NW * 32;
    constexpr int ACH = 16;                      // A chunks per K-step (128r x 128B)
    constexpr int NCH = ACH + BNT / 8;           // + B chunks
    __shared__ __align__(16) __bf16 sA[2][128 * 64];
    __shared__ __align__(16) __bf16 sB[2][BNT * 64];
    int tid  = threadIdx.x;
    int wave = tid >> 6, lane = tid & 63;
    int m0 = blockIdx.y * 128, n0 = blockIdx.x * BNT;
    int wm = (wave & 1) * 64, wn = (wave >> 1) * (NW * 16);
    int lr = lane & 15;
    int lq = lane >> 4;
    int srow = lane >> 3;                        // row within a chunk (0..7)
    int sg   = ((lane & 7) ^ srow) * 8;          // swizzled source elem group

    auto stage = [&](int b, int k0) {
        for (int c = wave; c < NCH; c += 4) {
            if (c < ACH) {
                const __bf16* g = A + (size_t)(m0 + c * 8 + srow) * K + k0 + sg;
                async_cp16(&sA[b][c * 512], g);
            } else {
                int cb = c - ACH;
                const __bf16* g = Bb + (size_t)(n0 + cb * 8 + srow) * K + k0 + sg;
                async_cp16(&sB[b][cb * 512], g);
            }
        }
    };

    floatx4 acc[4][NW] = {};

    stage(0, 0);
    __builtin_amdgcn_sched_barrier(0);
    asm volatile("s_waitcnt vmcnt(0)" ::: "memory");
    __builtin_amdgcn_s_barrier();
    __builtin_amdgcn_sched_barrier(0);

    int cur = 0;
    for (int k0 = 0; k0 < K; k0 += 64) {
        if (k0 + 64 < K) stage(cur ^ 1, k0 + 64);   // prefetch overlaps compute

#pragma unroll
        for (int s = 0; s < 2; ++s) {
            bf16x8 af[4], bfr[NW];
#pragma unroll
            for (int i = 0; i < 4; ++i) {
                int row = wm + i * 16 + lr;
                af[i] = *(const bf16x8*)&sA[cur][row * 64 + (((s * 4 + lq) ^ (lr & 7)) * 8)];
            }
#pragma unroll
            for (int j = 0; j < NW; ++j) {
                int row = wn + j * 16 + lr;
                bfr[j] = *(const bf16x8*)&sB[cur][row * 64 + (((s * 4 + lq) ^ (lr & 7)) * 8)];
            }
#pragma unroll
            for (int i = 0; i < 4; ++i)
#pragma unroll
                for (int j = 0; j < NW; ++j)
                    acc[i][j] = __builtin_amdgcn_mfma_f32_16x16x32_bf16(af[i], bfr[j], acc[i][j], 0, 0, 0);
        }

        __builtin_amdgcn_sched_barrier(0);
        asm volatile("s_waitcnt vmcnt(0)" ::: "memory");
        __builtin_amdgcn_s_barrier();
        __builtin_amdgcn_sched_barrier(0);
        cur ^= 1;
    }

#pragma unroll
    for (int i = 0; i < 4; ++i)
#pragma unroll
        for (int j = 0; j < NW; ++j) {
            int gn = n0 + wn + j * 16 + lr;
#pragma unroll
            for (int r = 0; r < 4; ++r) {
                int gm = m0 + wm + i * 16 + lq * 4 + r;
                float v = acc[i][j][r];
                if (EPI == 1) {
                    if (gn < split) out0[(size_t)gm * split + gn] = (__bf16)v;
                    else            out1[(size_t)gm * split + (gn - split)] = (__bf16)v;
                } else {
                    size_t idx = (size_t)gm * N + gn;
                    outf[idx] = v + add[idx];
                }
            }
        }
}

// ---------------------------------------------------------------------------
// K3: depthwise causal conv (width 4) + bias + SiLU.  short8-vectorized:
// thread = 8 consecutive channels of one (b,l) row; 4 bf16x8 row loads.
// ---------------------------------------------------------------------------
__global__ __launch_bounds__(256) void conv_kernel(const __bf16* __restrict__ xin,
                                                   const float* __restrict__ cw,
                                                   const float* __restrict__ cb,
                                                   __bf16* __restrict__ u) {
    int t8 = blockIdx.x * 256 + threadIdx.x;         // over MROWS*DINNER/8
    int dg = t8 & (DINNER / 8 - 1);
    int bl = t8 >> 8;                                // b*SEQ + l
    int l  = bl & (SEQ - 1);
    int d0 = dg * 8;
    float acc[8];
#pragma unroll
    for (int k = 0; k < 8; ++k) acc[k] = cb[d0 + k];
    float wgt[8][4];
#pragma unroll
    for (int k = 0; k < 8; ++k) {
        floatx4 wv = *(const floatx4*)&cw[(d0 + k) * 4];
#pragma unroll
        for (int j = 0; j < 4; ++j) wgt[k][j] = wv[j];
    }
#pragma unroll
    for (int j = 0; j < 4; ++j) {
        int ll = l - 3 + j;
        if (ll >= 0) {
            bf16x8 v = *(const bf16x8*)&xin[(size_t)(bl - 3 + j) * DINNER + d0];
#pragma unroll
            for (int k = 0; k < 8; ++k) acc[k] += (float)v[k] * wgt[k][j];
        }
    }
    __bf16 r[8];
#pragma unroll
    for (int k = 0; k < 8; ++k) {
        float sg = 1.f / (1.f + __expf(-acc[k]));
        r[k] = (__bf16)(acc[k] * sg);
    }
    *(bf16x8*)&u[(size_t)bl * DINNER + d0] = *(bf16x8*)r;
}

// ---------------------------------------------------------------------------
// K4 (MFMA, split-K): P[ks][4096,96] = u[4096,2048](K-slice ks) @ Wx^T.
// Partial STORES (no atomics).  WX_KS=8 -> partials 12 MiB.  wx_reduce sums.
// ---------------------------------------------------------------------------
#define BM 128
#define BN 128
#define BK 32
#define LDK 48
#define WX_KS 8
#define WX_KSLICE (DINNER / WX_KS)   // 256

__global__ __launch_bounds__(256) void wx_mfma(const __bf16* __restrict__ A,
                                               const float* __restrict__ B,
                                               float* __restrict__ P) {
    __shared__ __align__(16) __bf16 sA[BM][LDK];
    __shared__ __align__(16) __bf16 sB[96][LDK];
    int tid  = threadIdx.x;
    int wave = tid >> 6, lane = tid & 63;
    int m0 = blockIdx.x * BM;
    int k0base = blockIdx.y * WX_KSLICE;
    int wm = (wave & 1) * 64, wn = (wave >> 1) * 48;
    int lr = lane & 15;
    int lq = lane >> 4;

    floatx4 acc[4][3] = {};

    for (int k0 = k0base; k0 < k0base + WX_KSLICE; k0 += BK) {
#pragma unroll
        for (int c = tid; c < 512; c += 256) {
            int row = c >> 2, col = (c & 3) * 8;
            *(bf16x8*)&sA[row][col] = *(const bf16x8*)&A[(size_t)(m0 + row) * DINNER + k0 + col];
        }
        for (int c = tid; c < 384; c += 256) {
            int row = c >> 2, col = (c & 3) * 8;
            const float* src = B + (size_t)row * DINNER + k0 + col;
            floatx4 lo = *(const floatx4*)src;
            floatx4 hi = *(const floatx4*)(src + 4);
            bf16x8 v;
#pragma unroll
            for (int t = 0; t < 4; ++t) { v[t] = (__bf16)lo[t]; v[4 + t] = (__bf16)hi[t]; }
            *(bf16x8*)&sB[row][col] = v;
        }
        __syncthreads();

        bf16x8 af[4], bfr[3];
#pragma unroll
        for (int i = 0; i < 4; ++i) af[i]  = *(const bf16x8*)&sA[wm + i * 16 + lr][lq * 8];
#pragma unroll
        for (int j = 0; j < 3; ++j) bfr[j] = *(const bf16x8*)&sB[wn + j * 16 + lr][lq * 8];
#pragma unroll
        for (int i = 0; i < 4; ++i)
#pragma unroll
            for (int j = 0; j < 3; ++j)
                acc[i][j] = __builtin_amdgcn_mfma_f32_16x16x32_bf16(af[i], bfr[j], acc[i][j], 0, 0, 0);
        __syncthreads();
    }

    float* Pk = P + (size_t)blockIdx.y * (MROWS * 96);
#pragma unroll
    for (int i = 0; i < 4; ++i)
#pragma unroll
        for (int j = 0; j < 3; ++j) {
            int gn = wn + j * 16 + lr;
#pragma unroll
            for (int r = 0; r < 4; ++r) {
                int gm = m0 + wm + i * 16 + lq * 4 + r;
                Pk[(size_t)gm * 96 + gn] = acc[i][j][r];
            }
        }
}

__global__ __launch_bounds__(256) void wx_reduce(const float* __restrict__ P,
                                                 float* __restrict__ xdbl) {
    int i = (blockIdx.x * 256 + threadIdx.x) * 4;    // over MROWS*96
    floatx4 s = *(const floatx4*)&P[i];
#pragma unroll
    for (int k = 1; k < WX_KS; ++k) {
        floatx4 v = *(const floatx4*)&P[(size_t)k * (MROWS * 96) + i];
        s += v;
    }
    *(floatx4*)&xdbl[i] = s;
}

// ---------------------------------------------------------------------------
// K5 (MFMA): dt[4096,2048] = softplus(xdbl[:,0:64] @ Wdt[2048,64]^T + b_dt)
// ---------------------------------------------------------------------------
__global__ __launch_bounds__(256) void dt_mfma(const float* __restrict__ Af,
                                               const float* __restrict__ B,
                                               const float* __restrict__ bdt,
                                               __bf16* __restrict__ dt) {
    __shared__ __align__(16) __bf16 sA[BM][LDK];
    __shared__ __align__(16) __bf16 sB[BN][LDK];
    int tid  = threadIdx.x;
    int wave = tid >> 6, lane = tid & 63;
    int m0 = blockIdx.y * BM, n0 = blockIdx.x * BN;
    int wm = (wave & 1) * 64, wn = (wave >> 1) * 64;
    int lr = lane & 15;
    int lq = lane >> 4;

    floatx4 acc[4][4] = {};

    for (int k0 = 0; k0 < DTRANK; k0 += BK) {
#pragma unroll
        for (int c = tid; c < 512; c += 256) {
            int row = c >> 2, col = (c & 3) * 8;
            const float* src = Af + (size_t)(m0 + row) * 96 + k0 + col;
            floatx4 lo = *(const floatx4*)src;
            floatx4 hi = *(const floatx4*)(src + 4);
            bf16x8 v;
#pragma unroll
            for (int t = 0; t < 4; ++t) { v[t] = (__bf16)lo[t]; v[4 + t] = (__bf16)hi[t]; }
            *(bf16x8*)&sA[row][col] = v;
        }
#pragma unroll
        for (int c = tid; c < 512; c += 256) {
            int row = c >> 2, col = (c & 3) * 8;
            const float* src = B + (size_t)(n0 + row) * DTRANK + k0 + col;
            floatx4 lo = *(const floatx4*)src;
            floatx4 hi = *(const floatx4*)(src + 4);
            bf16x8 v;
#pragma unroll
            for (int t = 0; t < 4; ++t) { v[t] = (__bf16)lo[t]; v[4 + t] = (__bf16)hi[t]; }
            *(bf16x8*)&sB[row][col] = v;
        }
        __syncthreads();

        bf16x8 af[4], bfr[4];
#pragma unroll
        for (int i = 0; i < 4; ++i) af[i]  = *(const bf16x8*)&sA[wm + i * 16 + lr][lq * 8];
#pragma unroll
        for (int j = 0; j < 4; ++j) bfr[j] = *(const bf16x8*)&sB[wn + j * 16 + lr][lq * 8];
#pragma unroll
        for (int i = 0; i < 4; ++i)
#pragma unroll
            for (int j = 0; j < 4; ++j)
                acc[i][j] = __builtin_amdgcn_mfma_f32_16x16x32_bf16(af[i], bfr[j], acc[i][j], 0, 0, 0);
        __syncthreads();
    }

#pragma unroll
    for (int i = 0; i < 4; ++i)
#pragma unroll
        for (int j = 0; j < 4; ++j) {
            int gn = n0 + wn + j * 16 + lr;
            float bv = bdt[gn];
#pragma unroll
            for (int r = 0; r < 4; ++r) {
                int gm = m0 + wm + i * 16 + lq * 4 + r;
                float a = acc[i][j][r] + bv;
                float sp = (a > 20.f) ? a : log1pf(__expf(a));
                dt[(size_t)gm * DINNER + gn] = (__bf16)sp;
            }
        }
}

// ---------------------------------------------------------------------------
// K6 (3-pass chunked scan), LDS-free.  Wave = 64 consecutive channels
// (coalesced dt/u/z loads, uniform B/C -> s_load), 16 states/lane.
// R20-proven depth-1 rotation; CLEN=32 -> 4096 waves (16/CU).
// ---------------------------------------------------------------------------
__global__ __launch_bounds__(64) void scan_pass1(const __bf16* __restrict__ dt,
                                                 const __bf16* __restrict__ u,
                                                 const float* __restrict__ xdbl,
                                                 const float* __restrict__ Alog,
                                                 float* __restrict__ Sdt,
                                                 __bf16* __restrict__ Hfix) {
    int c = blockIdx.x, dblk = blockIdx.y, b = blockIdx.z;
    int lane = threadIdx.x;
    int d = dblk * 64 + lane;
    int row0 = b * SEQ + c * CLEN;

    const __bf16* dtp = dt + (size_t)row0 * DINNER + d;
    const __bf16* up  = u  + (size_t)row0 * DINNER + d;
    const float*  bcp = xdbl + (size_t)row0 * 96 + 64;

    float A[DSTATE], h[DSTATE];
#pragma unroll
    for (int s = 0; s < DSTATE; ++s) { A[s] = -__expf(Alog[d * DSTATE + s]); h[s] = 0.f; }

    float S = 0.f;
    // prefetch t=0
    float dtv_n = (float)dtp[0];
    float uv_n  = (float)up[0];
    floatx4 B0n = *(const floatx4*)(bcp);
    floatx4 B1n = *(const floatx4*)(bcp + 4);
    floatx4 B2n = *(const floatx4*)(bcp + 8);
    floatx4 B3n = *(const floatx4*)(bcp + 12);
    for (int t = 0; t < CLEN; ++t) {
        float dtv = dtv_n, uv = uv_n;
        floatx4 B0 = B0n, B1 = B1n, B2 = B2n, B3 = B3n;
        if (t + 1 < CLEN) {                 // issue t+1 loads before t's chain
            dtv_n = (float)dtp[(size_t)(t + 1) * DINNER];
            uv_n  = (float)up [(size_t)(t + 1) * DINNER];
            B0n = *(const floatx4*)(bcp + (t + 1) * 96);
            B1n = *(const floatx4*)(bcp + (t + 1) * 96 + 4);
            B2n = *(const floatx4*)(bcp + (t + 1) * 96 + 8);
            B3n = *(const floatx4*)(bcp + (t + 1) * 96 + 12);
        }
        S += dtv;
        float du = dtv * uv;
#pragma unroll
        for (int s = 0; s < 4; ++s) {
            h[s]      = __expf(dtv * A[s])      * h[s]      + du * B0[s];
            h[4 + s]  = __expf(dtv * A[4 + s])  * h[4 + s]  + du * B1[s];
            h[8 + s]  = __expf(dtv * A[8 + s])  * h[8 + s]  + du * B2[s];
            h[12 + s] = __expf(dtv * A[12 + s]) * h[12 + s] + du * B3[s];
        }
    }
    size_t ch = ((size_t)(b * DINNER + d) * CHUNKS + c);
    Sdt[ch] = S;
#pragma unroll
    for (int s = 0; s < DSTATE; ++s) Hfix[ch * DSTATE + s] = (__bf16)h[s];
}

__global__ __launch_bounds__(256) void scan_pass2(const float* __restrict__ Alog,
                                                  const float* __restrict__ Sdt,
                                                  __bf16* __restrict__ Hfix) {
    int g = blockIdx.x * 256 + threadIdx.x;       // over BATCH*DINNER*DSTATE
    int s = g & (DSTATE - 1);
    int bd = g >> 4;
    int d = bd & (DINNER - 1);
    float A = -__expf(Alog[d * DSTATE + s]);
    size_t hbase = (size_t)bd * CHUNKS * DSTATE + s;
    size_t sbase = (size_t)bd * CHUNKS;
    float h = 0.f;
#pragma unroll 4
    for (int c = 0; c < CHUNKS; ++c) {
        float Hl = (float)Hfix[hbase + c * DSTATE];
        float P  = __expf(A * Sdt[sbase + c]);
        Hfix[hbase + c * DSTATE] = (__bf16)h;
        h = P * h + Hl;
    }
}

__global__ __launch_bounds__(64) void scan_pass3(const __bf16* __restrict__ dt,
                                                 const __bf16* __restrict__ u,
                                                 const float* __restrict__ xdbl,
                                                 const float* __restrict__ Alog,
                                                 const float* __restrict__ Dp,
                                                 const __bf16* __restrict__ Hfix,
                                                 __bf16* zy) {
    int c = blockIdx.x, dblk = blockIdx.y, b = blockIdx.z;
    int lane = threadIdx.x;
    int d = dblk * 64 + lane;
    int row0 = b * SEQ + c * CLEN;

    const __bf16* dtp = dt + (size_t)row0 * DINNER + d;
    const __bf16* up  = u  + (size_t)row0 * DINNER + d;
    __bf16*       zyp = zy + (size_t)row0 * DINNER + d;
    const float*  bcp = xdbl + (size_t)row0 * 96 + 64;

    float A[DSTATE], h[DSTATE];
    size_t ch = ((size_t)(b * DINNER + d) * CHUNKS + c);
#pragma unroll
    for (int s = 0; s < DSTATE; ++s) {
        A[s] = -__expf(Alog[d * DSTATE + s]);
        h[s] = (float)Hfix[ch * DSTATE + s];
    }
    float Dv = Dp[d];

    // prefetch t=0
    float dtv_n = (float)dtp[0];
    float uv_n  = (float)up[0];
    float zv_n  = (float)zyp[0];
    floatx4 B0n = *(const floatx4*)(bcp);
    floatx4 B1n = *(const floatx4*)(bcp + 4);
    floatx4 B2n = *(const floatx4*)(bcp + 8);
    floatx4 B3n = *(const floatx4*)(bcp + 12);
    floatx4 C0n = *(const floatx4*)(bcp + 16);
    floatx4 C1n = *(const floatx4*)(bcp + 20);
    floatx4 C2n = *(const floatx4*)(bcp + 24);
    floatx4 C3n = *(const floatx4*)(bcp + 28);
    for (int t = 0; t < CLEN; ++t) {
        float dtv = dtv_n, uv = uv_n, zv = zv_n;
        floatx4 B0 = B0n, B1 = B1n, B2 = B2n, B3 = B3n;
        floatx4 C0 = C0n, C1 = C1n, C2 = C2n, C3 = C3n;
        if (t + 1 < CLEN) {                 // issue t+1 loads before t's chain
            dtv_n = (float)dtp[(size_t)(t + 1) * DINNER];
            uv_n  = (float)up [(size_t)(t + 1) * DINNER];
            zv_n  = (float)zyp[(size_t)(t + 1) * DINNER];
            B0n = *(const floatx4*)(bcp + (t + 1) * 96);
            B1n = *(const floatx4*)(bcp + (t + 1) * 96 + 4);
            B2n = *(const floatx4*)(bcp + (t + 1) * 96 + 8);
            B3n = *(const floatx4*)(bcp + (t + 1) * 96 + 12);
            C0n = *(const floatx4*)(bcp + (t + 1) * 96 + 16);
            C1n = *(const floatx4*)(bcp + (t + 1) * 96 + 20);
            C2n = *(const floatx4*)(bcp + (t + 1) * 96 + 24);
            C3n = *(const floatx4*)(bcp + (t + 1) * 96 + 28);
        }
        float du = dtv * uv;
        float yv = 0.f;
#pragma unroll
        for (int s = 0; s < 4; ++s) {
            h[s]      = __expf(dtv * A[s])      * h[s]      + du * B0[s];
            h[4 + s]  = __expf(dtv * A[4 + s])  * h[4 + s]  + du * B1[s];
            h[8 + s]  = __expf(dtv * A[8 + s])  * h[8 + s]  + du * B2[s];
            h[12 + s] = __expf(dtv * A[12 + s]) * h[12 + s] + du * B3[s];
            yv += h[s] * C0[s] + h[4 + s] * C1[s] + h[8 + s] * C2[s] + h[12 + s] * C3[s];
        }
        float sg = zv / (1.f + __expf(-zv));
        zyp[(size_t)t * DINNER] = (__bf16)((yv + uv * Dv) * sg);
    }
}

// ---------------------------------------------------------------------------
extern "C" void kernel_launch(void* const* d_in, const int* in_sizes, int n_in,
                              void* d_out, int out_size, void* d_ws, size_t ws_size,
                              hipStream_t stream) {
    const float* x      = (const float*)d_in[0];
    const float* ln_w   = (const float*)d_in[1];
    const float* ln_b   = (const float*)d_in[2];
    const float* W_in   = (const float*)d_in[3];
    const float* conv_w = (const float*)d_in[4];
    const float* conv_b = (const float*)d_in[5];
    const float* W_x    = (const float*)d_in[6];
    const float* W_dt   = (const float*)d_in[7];
    const float* b_dt   = (const float*)d_in[8];
    const float* A_log  = (const float*)d_in[9];
    const float* Dp     = (const float*)d_in[10];
    const float* W_out  = (const float*)d_in[11];
    float* out = (float*)d_out;

    // Workspace, 56 MiB peak:
    //   [ 0,  8M)  xn bf16 (dead after GEMM1) -> { xdbl fp32 [0,1.5M),
    //              Sdt fp32 [1.5M,2.5M) }
    //   [ 8M,24M)  x_in bf16 (dead after conv) -> wxP fp32 12M (wx..reduce)
    //              -> dt bf16 (dt_mfma..pass3)
    //   [24M,40M)  z bf16; scan pass3 overwrites with y in place
    //   [40M,56M)  Winb bf16 8M (dead after GEMM1) -> u bf16 16M (conv..pass3)
    //              -> Woutb bf16 4M (after pass3)
    //   Hfix bf16 8.4M lives in d_out (dead until final GEMM2 overwrites it).
    char* ws = (char*)d_ws;
    __bf16* xn_bf  = (__bf16*)(ws);
    float*  xdbl   = (float*) (ws);
    float*  Sdt    = (float*) (ws + 1536ull * 1024);
    __bf16* Hfix   = (__bf16*)(d_out);
    __bf16* xin_bf = (__bf16*)(ws + (8ull  << 20));
    float*  wxP    = (float*) (ws + (8ull  << 20));
    __bf16* dt_bf  = (__bf16*)(ws + (8ull  << 20));
    __bf16* zy_bf  = (__bf16*)(ws + (24ull << 20));
    __bf16* Winb   = (__bf16*)(ws + (40ull << 20));
    __bf16* u_bf   = (__bf16*)(ws + (40ull << 20));
    __bf16* Woutb  = (__bf16*)(ws + (40ull << 20));

    ln_kernel<<<MROWS, 256, 0, stream>>>(x, ln_w, ln_b, xn_bf);

    w2bf<<<(2 * DINNER * DMODEL) / 1024, 256, 0, stream>>>(W_in, Winb, 2 * DINNER * DMODEL);

    // GEMM1: 8-phase 256x256 template, grid = 16x16 = 256 blocks (1/CU)
    gemm8p<1><<<(MROWS / 256) * (2 * DINNER / 256), 512, 0, stream>>>(
        xn_bf, Winb, MROWS, 2 * DINNER, DMODEL, xin_bf, zy_bf, DINNER);

    conv_kernel<<<MROWS * DINNER / (8 * 256), 256, 0, stream>>>(xin_bf, conv_w, conv_b, u_bf);

    // wx: split-K partial stores (no atomics, no memset), then reduce
    wx_mfma<<<dim3(MROWS / BM, WX_KS), 256, 0, stream>>>(u_bf, W_x, wxP);
    wx_reduce<<<(MROWS * 96) / 1024, 256, 0, stream>>>(wxP, xdbl);

    dt_mfma<<<dim3(DINNER / BN, MROWS / BM), 256, 0, stream>>>(xdbl, W_dt, b_dt, dt_bf);

    dim3 sgrid(CHUNKS, DINNER / 64, BATCH);
    scan_pass1<<<sgrid, 64, 0, stream>>>(dt_bf, u_bf, xdbl, A_log, Sdt, Hfix);
    scan_pass2<<<BATCH * DINNER * DSTATE / 256, 256, 0, stream>>>(A_log, Sdt, Hfix);
    scan_pass3<<<sgrid, 64, 0, stream>>>(dt_bf, u_bf, xdbl, A_log, Dp, Hfix, zy_bf);

    w2bf<<<(DMODEL * DINNER) / 1024, 256, 0, stream>>>(W_out, Woutb, DMODEL * DINNER);

    // GEMM2: gemm_as NW=2 double-buffered prefetch (512 blocks = 2/CU);
    // fully overwrites d_out (incl. the Hfix scratch region).
    gemm_as<2, 2><<<dim3(DMODEL / 64, MROWS / 128), 256, 0, stream>>>(
        zy_bf, Woutb, MROWS, DMODEL, DINNER, nullptr, nullptr, out, x, 0);
}